// Round 10
// baseline (377.256 us; speedup 1.0000x reference)
//
#include <hip/hip_runtime.h>

typedef unsigned short u16;
typedef __attribute__((ext_vector_type(4))) float f32x4;
typedef _Float16 f16x8 __attribute__((ext_vector_type(8)));
typedef __attribute__((ext_vector_type(4))) u16   u16x4;
typedef __attribute__((ext_vector_type(8))) u16   u16x8;

#define DEV static __device__ __forceinline__

constexpr int Ll = 4096;

DEV float h2f(u16 v) { _Float16 h; __builtin_memcpy(&h, &v, 2); return (float)h; }
DEV u16 f2h(float f) { _Float16 h = (_Float16)f; u16 u; __builtin_memcpy(&u, &h, 2); return u; }

DEV f32x4 mfma16h(f16x8 a, f16x8 b, f32x4 c) {
    return __builtin_amdgcn_mfma_f32_16x16x32_f16(a, b, c, 0, 0, 0);
}

#if defined(__has_builtin)
#if __has_builtin(__builtin_amdgcn_global_load_lds)
#define HAS_GLLDS 1
#endif
#endif
#ifndef HAS_GLLDS
#define HAS_GLLDS 0
#endif

#define SBAR()  __builtin_amdgcn_s_barrier()
#define SCHED() __builtin_amdgcn_sched_barrier(0)
#define LGKM0() asm volatile("s_waitcnt lgkmcnt(0)" ::: "memory")

// ---- m201-style stage: one region (256 rows x 32 cols fp16 = 16KB) = 2 gload units.
#if HAS_GLLDS
#define STG2(BUF, REG, SRC, ROWBASE, TK, KS)                                         \
  { _Pragma("unroll") for (int u_ = 0; u_ < 2; u_++) {                               \
      int row_ = u_ * 128 + wave * 16 + (lane >> 2);                                 \
      int c_ = lane & 3;                                                             \
      const u16* gp_ = (SRC) + (size_t)((ROWBASE) + row_) * 1024 + (TK) * 64         \
                        + (KS) * 32 + ((c_ ^ ((row_ >> 1) & 3)) * 8);                \
      __builtin_amdgcn_global_load_lds(                                              \
        (const __attribute__((address_space(1))) unsigned int*)gp_,                  \
        (__attribute__((address_space(3))) unsigned int*)(sm + (BUF) * 32768 +       \
          (REG) * 8192 + (u_ * 512 + wave * 64) * 8), 16, 0, 0); } }
#else
#define STG2(BUF, REG, SRC, ROWBASE, TK, KS)                                         \
  { _Pragma("unroll") for (int u_ = 0; u_ < 2; u_++) {                               \
      int row_ = u_ * 128 + wave * 16 + (lane >> 2);                                 \
      int c_ = lane & 3;                                                             \
      const u16* gp_ = (SRC) + (size_t)((ROWBASE) + row_) * 1024 + (TK) * 64         \
                        + (KS) * 32 + ((c_ ^ ((row_ >> 1) & 3)) * 8);                \
      *(u16x8*)(sm + (BUF) * 32768 + (REG) * 8192 + (u_ * 512 + wave * 64 + lane) * 8) \
          = *(const u16x8*)gp_; } }
#endif

// ---------------- merged prep: x, Wq|Wk|Wv|Wo, omega ----------------
__global__ __launch_bounds__(256) void k_prep(
    const float* __restrict__ x, const float* __restrict__ Wq, const float* __restrict__ Wk,
    const float* __restrict__ Wv, const float* __restrict__ Wo, const float* __restrict__ om,
    u16* __restrict__ xh, u16* __restrict__ Wc, u16* __restrict__ wtp) {
    int bx = blockIdx.x, tid = threadIdx.x;
    if (bx < 16384) {
        size_t i = ((size_t)bx * 256 + tid) * 4;
        f32x4 v = *(const f32x4*)(x + i);
        u16x4 h;
#pragma unroll
        for (int j = 0; j < 4; j++) h[j] = f2h(v[j]);
        *(u16x4*)(xh + i) = h;
    } else if (bx < 20480) {
        int wsel = (bx - 16384) >> 10;
        const float* src = (wsel == 0) ? Wq : (wsel == 1) ? Wk : (wsel == 2) ? Wv : Wo;
        size_t i = ((size_t)((bx - 16384) & 1023) * 256 + tid) * 4;
        f32x4 v = *(const f32x4*)(src + i);
        u16x4 h;
#pragma unroll
        for (int j = 0; j < 4; j++) h[j] = f2h(v[j]);
        *(u16x4*)(Wc + (size_t)wsel * 1048576 + i) = h;
    } else {
        int i = (bx - 20480) * 256 + tid; // 16384
        int m = i >> 6, d = i & 63;
        wtp[i] = f2h(om[d * 256 + m] * 0.35355339059327373f);
    }
}

// ---------------- QKV GEMM: 256x256, BK=64, 8-phase, counted vmcnt (r8, frozen) ----------------
__global__ __launch_bounds__(512, 1) void k_gemm_qkv(
    const u16* __restrict__ Ax, const u16* __restrict__ Bw,
    u16* __restrict__ QK, u16* __restrict__ Vb) {
    __shared__ __align__(16) u16 sm[65536]; // 128 KB
    const int tid = threadIdx.x, wave = tid >> 6, lane = tid & 63;
    const int lr = lane & 15, lkq = lane >> 4;
    const int wr = wave >> 2, wc = wave & 3;
    const int m0 = blockIdx.y * 256, n0 = blockIdx.x * 256;
    const int sec = n0 >> 10;

    const int arow = wr * 128 + lr;
    const int aBase = arow * 32 + ((lkq ^ ((arow >> 1) & 3)) * 8);
    const int brow = wc * 64 + lr;
    const int bBase = 16384 + brow * 32 + ((lkq ^ ((brow >> 1) & 3)) * 8);

    f32x4 acc[8][4];
#pragma unroll
    for (int i = 0; i < 8; i++)
#pragma unroll
        for (int j = 0; j < 4; j++)
#pragma unroll
            for (int r = 0; r < 4; r++) acc[i][j][r] = 0.f;

    STG2(0, 0, Ax, m0, 0, 0)
    STG2(0, 2, Bw, n0, 0, 0)
    STG2(0, 1, Ax, m0, 0, 1)
    STG2(0, 3, Bw, n0, 0, 1)
    asm volatile("s_waitcnt vmcnt(4)" ::: "memory");
    SCHED(); SBAR(); SCHED();

    f16x8 bfr[2][4], afr[4];
    for (int t = 0; t < 16; ++t) {
        const u16* bp = sm + (t & 1) * 32768;
        const int nb = (t + 1) & 1;
        const bool st = t < 15;
#pragma unroll
        for (int f = 0; f < 4; f++) afr[f] = *(const f16x8*)&bp[aBase + f * 512];
#pragma unroll
        for (int j = 0; j < 4; j++) bfr[0][j] = *(const f16x8*)&bp[bBase + j * 512];
        if (st) STG2(nb, 0, Ax, m0, t + 1, 0)
        SBAR(); LGKM0(); SCHED();
        __builtin_amdgcn_s_setprio(1);
#pragma unroll
        for (int i = 0; i < 4; i++)
#pragma unroll
            for (int j = 0; j < 4; j++)
                acc[i][j] = mfma16h(afr[i], bfr[0][j], acc[i][j]);
        __builtin_amdgcn_s_setprio(0);
        SCHED();
        if (st) { asm volatile("s_waitcnt vmcnt(2)" ::: "memory"); }
        else    { asm volatile("s_waitcnt vmcnt(0)" ::: "memory"); }
        SCHED(); SBAR(); SCHED();
#pragma unroll
        for (int f = 0; f < 4; f++) afr[f] = *(const f16x8*)&bp[aBase + 8192 + f * 512];
#pragma unroll
        for (int j = 0; j < 4; j++) bfr[1][j] = *(const f16x8*)&bp[bBase + 8192 + j * 512];
        if (st) STG2(nb, 2, Bw, n0, t + 1, 0)
        SBAR(); LGKM0(); SCHED();
        __builtin_amdgcn_s_setprio(1);
#pragma unroll
        for (int i = 0; i < 4; i++)
#pragma unroll
            for (int j = 0; j < 4; j++)
                acc[i][j] = mfma16h(afr[i], bfr[1][j], acc[i][j]);
        __builtin_amdgcn_s_setprio(0);
        SCHED(); SBAR(); SCHED();
#pragma unroll
        for (int f = 0; f < 4; f++) afr[f] = *(const f16x8*)&bp[aBase + 2048 + f * 512];
        if (st) STG2(nb, 1, Ax, m0, t + 1, 1)
        SBAR(); LGKM0(); SCHED();
        __builtin_amdgcn_s_setprio(1);
#pragma unroll
        for (int i = 0; i < 4; i++)
#pragma unroll
            for (int j = 0; j < 4; j++)
                acc[4 + i][j] = mfma16h(afr[i], bfr[0][j], acc[4 + i][j]);
        __builtin_amdgcn_s_setprio(0);
        SCHED(); SBAR(); SCHED();
#pragma unroll
        for (int f = 0; f < 4; f++) afr[f] = *(const f16x8*)&bp[aBase + 8192 + 2048 + f * 512];
        if (st) STG2(nb, 3, Bw, n0, t + 1, 1)
        SBAR(); LGKM0(); SCHED();
        __builtin_amdgcn_s_setprio(1);
#pragma unroll
        for (int i = 0; i < 4; i++)
#pragma unroll
            for (int j = 0; j < 4; j++)
                acc[4 + i][j] = mfma16h(afr[i], bfr[1][j], acc[4 + i][j]);
        __builtin_amdgcn_s_setprio(0);
        SCHED();
        if (st) { asm volatile("s_waitcnt vmcnt(4)" ::: "memory"); }
        SCHED(); SBAR(); SCHED();
    }

    float* ep = (float*)sm; // [32][264]
    for (int g = 0; g < 8; g++) {
        __syncthreads();
        if (wr == (g >> 2)) {
#pragma unroll
            for (int fi = 0; fi < 2; fi++) {
                int fm = (g & 3) * 2 + fi;
#pragma unroll
                for (int fn = 0; fn < 4; fn++)
#pragma unroll
                    for (int r = 0; r < 4; r++)
                        ep[(fi * 16 + (lane >> 4) * 4 + r) * 264 + wc * 64 + fn * 16 + lr] = acc[fm][fn][r];
            }
        }
        __syncthreads();
        int row = tid >> 4, c0 = (tid & 15) * 16;
        int grow = m0 + g * 32 + row;
        u16x8 h0, h1;
#pragma unroll
        for (int j = 0; j < 8; j++) {
            h0[j] = f2h(ep[row * 264 + c0 + j]);
            h1[j] = f2h(ep[row * 264 + c0 + 8 + j]);
        }
        if (sec < 2) {
            size_t o = (size_t)grow * 2048 + (n0 + c0);
            *(u16x8*)(QK + o) = h0; *(u16x8*)(QK + o + 8) = h1;
        } else {
            size_t o = (size_t)grow * 1024 + (n0 - 2048 + c0);
            *(u16x8*)(Vb + o) = h0; *(u16x8*)(Vb + o + 8) = h1;
        }
    }
}

// ---------------- final GEMM: attn @ Wo^T + bo -> f32 out (4-phase BK=64, counted vmcnt) ----------------
__global__ __launch_bounds__(512, 1) void k_gemm_out(
    const u16* __restrict__ Ab, const u16* __restrict__ Bw,
    const float* __restrict__ bias, float* __restrict__ outp) {
    __shared__ __align__(16) u16 sm[65536]; // 128 KB
    const int tid = threadIdx.x, wave = tid >> 6, lane = tid & 63;
    const int lr = lane & 15, lkq = lane >> 4;
    const int wr = wave >> 2, wc = wave & 3;
    const int m0 = blockIdx.y * 256, n0 = blockIdx.x * 256;

    const int arow = wr * 128 + lr;
    const int aBase = arow * 32 + ((lkq ^ ((arow >> 1) & 3)) * 8);
    const int brow = wc * 64 + lr;
    const int bBase = 16384 + brow * 32 + ((lkq ^ ((brow >> 1) & 3)) * 8);

    f32x4 acc[8][4];
#pragma unroll
    for (int i = 0; i < 8; i++)
#pragma unroll
        for (int j = 0; j < 4; j++)
#pragma unroll
            for (int r = 0; r < 4; r++) acc[i][j][r] = 0.f;

    STG2(0, 0, Ab, m0, 0, 0)
    STG2(0, 2, Bw, n0, 0, 0)
    STG2(0, 1, Ab, m0, 0, 1)
    STG2(0, 3, Bw, n0, 0, 1)
    asm volatile("s_waitcnt vmcnt(4)" ::: "memory");
    SCHED(); SBAR(); SCHED();

    f16x8 bfr[2][4], afr[4];
    for (int t = 0; t < 16; ++t) {
        const u16* bp = sm + (t & 1) * 32768;
        const int nb = (t + 1) & 1;
        const bool st = t < 15;
#pragma unroll
        for (int f = 0; f < 4; f++) afr[f] = *(const f16x8*)&bp[aBase + f * 512];
#pragma unroll
        for (int j = 0; j < 4; j++) bfr[0][j] = *(const f16x8*)&bp[bBase + j * 512];
        if (st) STG2(nb, 0, Ab, m0, t + 1, 0)
        SBAR(); LGKM0(); SCHED();
        __builtin_amdgcn_s_setprio(1);
#pragma unroll
        for (int i = 0; i < 4; i++)
#pragma unroll
            for (int j = 0; j < 4; j++)
                acc[i][j] = mfma16h(afr[i], bfr[0][j], acc[i][j]);
        __builtin_amdgcn_s_setprio(0);
        SCHED();
        if (st) { asm volatile("s_waitcnt vmcnt(2)" ::: "memory"); }
        else    { asm volatile("s_waitcnt vmcnt(0)" ::: "memory"); }
        SCHED(); SBAR(); SCHED();
#pragma unroll
        for (int f = 0; f < 4; f++) afr[f] = *(const f16x8*)&bp[aBase + 8192 + f * 512];
#pragma unroll
        for (int j = 0; j < 4; j++) bfr[1][j] = *(const f16x8*)&bp[bBase + 8192 + j * 512];
        if (st) STG2(nb, 2, Bw, n0, t + 1, 0)
        SBAR(); LGKM0(); SCHED();
        __builtin_amdgcn_s_setprio(1);
#pragma unroll
        for (int i = 0; i < 4; i++)
#pragma unroll
            for (int j = 0; j < 4; j++)
                acc[i][j] = mfma16h(afr[i], bfr[1][j], acc[i][j]);
        __builtin_amdgcn_s_setprio(0);
        SCHED(); SBAR(); SCHED();
#pragma unroll
        for (int f = 0; f < 4; f++) afr[f] = *(const f16x8*)&bp[aBase + 2048 + f * 512];
        if (st) STG2(nb, 1, Ab, m0, t + 1, 1)
        SBAR(); LGKM0(); SCHED();
        __builtin_amdgcn_s_setprio(1);
#pragma unroll
        for (int i = 0; i < 4; i++)
#pragma unroll
            for (int j = 0; j < 4; j++)
                acc[4 + i][j] = mfma16h(afr[i], bfr[0][j], acc[4 + i][j]);
        __builtin_amdgcn_s_setprio(0);
        SCHED(); SBAR(); SCHED();
#pragma unroll
        for (int f = 0; f < 4; f++) afr[f] = *(const f16x8*)&bp[aBase + 8192 + 2048 + f * 512];
        if (st) STG2(nb, 3, Bw, n0, t + 1, 1)
        SBAR(); LGKM0(); SCHED();
        __builtin_amdgcn_s_setprio(1);
#pragma unroll
        for (int i = 0; i < 4; i++)
#pragma unroll
            for (int j = 0; j < 4; j++)
                acc[4 + i][j] = mfma16h(afr[i], bfr[1][j], acc[4 + i][j]);
        __builtin_amdgcn_s_setprio(0);
        SCHED();
        if (st) { asm volatile("s_waitcnt vmcnt(4)" ::: "memory"); }
        SCHED(); SBAR(); SCHED();
    }

    float* ep = (float*)sm; // [32][264]
    for (int g = 0; g < 8; g++) {
        __syncthreads();
        if (wr == (g >> 2)) {
#pragma unroll
            for (int fi = 0; fi < 2; fi++) {
                int fm = (g & 3) * 2 + fi;
#pragma unroll
                for (int fn = 0; fn < 4; fn++)
#pragma unroll
                    for (int r = 0; r < 4; r++)
                        ep[(fi * 16 + (lane >> 4) * 4 + r) * 264 + wc * 64 + fn * 16 + lr] = acc[fm][fn][r];
            }
        }
        __syncthreads();
        int row = tid >> 4, c0 = (tid & 15) * 16;
        int grow = m0 + g * 32 + row;
        float vv[16];
#pragma unroll
        for (int j = 0; j < 16; j++) vv[j] = ep[row * 264 + c0 + j] + bias[n0 + c0 + j];
#pragma unroll
        for (int p = 0; p < 4; p++) {
            f32x4 tv;
#pragma unroll
            for (int q = 0; q < 4; q++) tv[q] = vv[p * 4 + q];
            *(f32x4*)(outp + (size_t)grow * 1024 + n0 + c0 + p * 4) = tv;
        }
    }
}

// ---------------- fused phi(K) + KV + Ksum: sliced sKfT (36.5KB LDS -> 4 blocks/CU) ----------------
__global__ __launch_bounds__(256) void k_phik_kv(
    const u16* __restrict__ QK, const u16* __restrict__ wt,
    const u16* __restrict__ Vb, float* __restrict__ KVacc, float* __restrict__ Ksum) {
    __shared__ __align__(16) u16 sKh[64 * 72];    // 9 KB
    __shared__ __align__(16) u16 sVt[64 * 72];    // 9 KB
    __shared__ __align__(16) u16 sKfT[256 * 36];  // 18 KB, one ks-slice (reused)
    __shared__ float snsq[64];
    const int tid = threadIdx.x, wave = tid >> 6, lane = tid & 63;
    const int lr = lane & 15, lk = (lane >> 4) * 8;
    const int kc = blockIdx.x, bh = blockIdx.y;
    const int b = bh >> 4, h = bh & 15;

    f16x8 wb[4][2];
#pragma unroll
    for (int fn = 0; fn < 4; fn++)
#pragma unroll
        for (int ks = 0; ks < 2; ks++)
            wb[fn][ks] = *(const f16x8*)(wt + (size_t)(wave * 64 + fn * 16 + lr) * 64 + ks * 32 + lk);

    f32x4 akv[4][4];
#pragma unroll
    for (int i = 0; i < 4; i++)
#pragma unroll
        for (int j = 0; j < 4; j++)
#pragma unroll
            for (int r = 0; r < 4; r++) akv[i][j][r] = 0.f;
    float ksm[4] = {0.f, 0.f, 0.f, 0.f};

    // prefetch regs for iteration 0
    const int rowS = tid >> 2, cS = (tid & 3) * 16;
    size_t gK = ((size_t)(b * Ll + kc * 256 + rowS)) * 2048 + 1024 + h * 64 + cS;
    size_t gV = ((size_t)(b * Ll + kc * 256 + rowS)) * 1024 + h * 64 + cS;
    u16x8 kh0 = *(const u16x8*)(QK + gK);
    u16x8 kh1 = *(const u16x8*)(QK + gK + 8);
    u16x8 vv0 = *(const u16x8*)(Vb + gV);
    u16x8 vv1 = *(const u16x8*)(Vb + gV + 8);

    for (int it = 0; it < 4; it++) {
        __syncthreads();
        { // write K stage + nsq from regs
            *(u16x8*)&sKh[rowS * 72 + cS]     = kh0;
            *(u16x8*)&sKh[rowS * 72 + cS + 8] = kh1;
            float s = 0.f;
#pragma unroll
            for (int j = 0; j < 8; j++) {
                float a = h2f(kh0[j]); s += a * a;
                float c = h2f(kh1[j]); s += c * c;
            }
            s += __shfl_xor(s, 1); s += __shfl_xor(s, 2);
            if ((tid & 3) == 0) snsq[rowS] = s * 0.0625f;
        }
        { // write V transposed from regs
#pragma unroll
            for (int j = 0; j < 8; j++) {
                sVt[(cS + j) * 72 + rowS]     = vv0[j];
                sVt[(cS + 8 + j) * 72 + rowS] = vv1[j];
            }
        }
        __syncthreads();
        if (it < 3) { // issue next-iteration loads; land under MFMA phases
            gK += 131072; gV += 65536;
            kh0 = *(const u16x8*)(QK + gK);
            kh1 = *(const u16x8*)(QK + gK + 8);
            vv0 = *(const u16x8*)(Vb + gV);
            vv1 = *(const u16x8*)(Vb + gV + 8);
        }
        // two ks-slices: phi for fm=2p,2p+1 -> sKfT slice -> KV ks=p (wave-local, no barrier)
#pragma unroll
        for (int p = 0; p < 2; p++) {
#pragma unroll
            for (int fm2 = 0; fm2 < 2; fm2++) {
                int fm = p * 2 + fm2;
                f32x4 ap[4];
#pragma unroll
                for (int fn = 0; fn < 4; fn++)
#pragma unroll
                    for (int r = 0; r < 4; r++) ap[fn][r] = 0.f;
#pragma unroll
                for (int ks = 0; ks < 2; ks++) {
                    f16x8 aH = *(const f16x8*)&sKh[(fm * 16 + lr) * 72 + ks * 32 + lk];
#pragma unroll
                    for (int fn = 0; fn < 4; fn++)
                        ap[fn] = mfma16h(aH, wb[fn][ks], ap[fn]);
                }
#pragma unroll
                for (int fn = 0; fn < 4; fn++) {
                    u16x4 pk;
#pragma unroll
                    for (int r = 0; r < 4; r++) {
                        float ns = snsq[fm * 16 + (lane >> 4) * 4 + r];
                        float val = __expf(ap[fn][r] - ns) * 0.00390625f; // 1/256
                        ksm[fn] += val;
                        pk[r] = f2h(val);
                    }
                    *(u16x4*)&sKfT[(wave * 64 + fn * 16 + lr) * 36 + fm2 * 16 + (lane >> 4) * 4] = pk;
                }
            }
            // KV MFMA for ks-slice p (reads own wave's sKfT rows; sVt k-halfs p*32..)
            f16x8 a4[4], b4[4];
#pragma unroll
            for (int f = 0; f < 4; f++) {
                a4[f] = *(const f16x8*)&sKfT[(wave * 64 + f * 16 + lr) * 36 + lk];
                b4[f] = *(const f16x8*)&sVt[(f * 16 + lr) * 72 + p * 32 + lk];
            }
#pragma unroll
            for (int fm = 0; fm < 4; fm++)
#pragma unroll
                for (int fn = 0; fn < 4; fn++)
                    akv[fm][fn] = mfma16h(a4[fm], b4[fn], akv[fm][fn]);
        }
    }
    // owned-slab stores (no atomics); 16 slabs
    const size_t base = ((size_t)(kc * 64 + bh)) << 14;
#pragma unroll
    for (int fm = 0; fm < 4; fm++)
#pragma unroll
        for (int fn = 0; fn < 4; fn++)
#pragma unroll
            for (int r = 0; r < 4; r++) {
                int m = wave * 64 + fm * 16 + (lane >> 4) * 4 + r;
                int d = fn * 16 + lr;
                KVacc[base + m * 64 + d] = akv[fm][fn][r];
            }
#pragma unroll
    for (int fn = 0; fn < 4; fn++) {
        ksm[fn] += __shfl_xor(ksm[fn], 16);
        ksm[fn] += __shfl_xor(ksm[fn], 32);
    }
    if (lane < 16) {
#pragma unroll
        for (int fn = 0; fn < 4; fn++)
            Ksum[(kc * 64 + bh) * 256 + wave * 64 + fn * 16 + lane] = ksm[fn];
    }
}

// ---------------- slab reduce: KVt[bh][d][m] = fp16(sum_kc KVacc), KsumR = sum_kc Ksum ----------------
__global__ __launch_bounds__(256) void k_kvt(const float* __restrict__ KVacc,
                                             const float* __restrict__ Ksum,
                                             u16* __restrict__ KVt, float* __restrict__ KsumR) {
    int i = blockIdx.x * 256 + threadIdx.x;
    if (blockIdx.x < 16384) {
        int bh = i >> 14, m = (i >> 6) & 255, d = i & 63;
        float s = 0.f;
#pragma unroll
        for (int kc = 0; kc < 16; kc++)
            s += KVacc[(((size_t)(kc * 64 + bh)) << 14) + m * 64 + d];
        KVt[((size_t)bh << 14) + d * 256 + m] = f2h(s);
    } else {
        int j = i - 4194304; // bh*256+m, 16384 total
        int bh = j >> 8, m = j & 255;
        float s = 0.f;
#pragma unroll
        for (int kc = 0; kc < 16; kc++)
            s += Ksum[(kc * 64 + bh) * 256 + m];
        KsumR[j] = s;
    }
}

// ---------------- fused phi(Q) + norm + attn: 4 subtiles/block, Q prefetch ----------------
__global__ __launch_bounds__(512) void k_phiq_attn(
    const u16* __restrict__ QK, const u16* __restrict__ wt,
    const u16* __restrict__ KVt, const float* __restrict__ Ksum,
    u16* __restrict__ attn) {
    __shared__ __align__(16) u16 sQh[64 * 72];
    __shared__ __align__(16) u16 sQf[64 * 264];
    __shared__ float sKs[256];
    __shared__ float snsq[64];
    __shared__ float snorm[64];
    const int tid = threadIdx.x, wave = tid >> 6, lane = tid & 63;
    const int lr = lane & 15, lk = (lane >> 4) * 8;
    const int bh = blockIdx.y, b = bh >> 4, h = bh & 15;
    const int mq = wave & 3;
    const int lh = wave >> 2;
    const int af = wave & 3;
    const int ad = wave >> 2;

    f16x8 wb[4][2];
#pragma unroll
    for (int fn = 0; fn < 4; fn++)
#pragma unroll
        for (int ks = 0; ks < 2; ks++)
            wb[fn][ks] = *(const f16x8*)(wt + (size_t)(mq * 64 + fn * 16 + lr) * 64 + ks * 32 + lk);
    f16x8 kvb[2][8];
#pragma unroll
    for (int fn = 0; fn < 2; fn++)
#pragma unroll
        for (int ks = 0; ks < 8; ks++)
            kvb[fn][ks] = *(const f16x8*)(KVt + ((size_t)bh << 14) +
                                          (size_t)(ad * 32 + fn * 16 + lr) * 256 + ks * 32 + lk);
    if (tid < 256) sKs[tid] = Ksum[bh * 256 + tid];

    // Q prefetch for st=0
    const int rowQ = tid >> 3, cQ = (tid & 7) * 8;
    size_t gQ = ((size_t)(b * Ll + blockIdx.x * 256 + rowQ)) * 2048 + h * 64 + cQ;
    u16x8 vh = *(const u16x8*)(QK + gQ);

    for (int st = 0; st < 4; st++) {
        const int l0 = blockIdx.x * 256 + st * 64;
        __syncthreads();
        { // stage Q + nsq from regs
            *(u16x8*)&sQh[rowQ * 72 + cQ] = vh;
            float s = 0.f;
#pragma unroll
            for (int j = 0; j < 8; j++) { float a = h2f(vh[j]); s += a * a; }
            s += __shfl_xor(s, 1); s += __shfl_xor(s, 2); s += __shfl_xor(s, 4);
            if ((tid & 7) == 0) snsq[rowQ] = s * 0.0625f;
        }
        __syncthreads();
#pragma unroll
        for (int fm = 0; fm < 2; fm++) {
            f32x4 ap[4];
#pragma unroll
            for (int fn = 0; fn < 4; fn++)
#pragma unroll
                for (int r = 0; r < 4; r++) ap[fn][r] = 0.f;
#pragma unroll
            for (int ks = 0; ks < 2; ks++) {
                f16x8 aH = *(const f16x8*)&sQh[(lh * 32 + fm * 16 + lr) * 72 + ks * 32 + lk];
#pragma unroll
                for (int fn = 0; fn < 4; fn++)
                    ap[fn] = mfma16h(aH, wb[fn][ks], ap[fn]);
            }
#pragma unroll
            for (int fn = 0; fn < 4; fn++)
#pragma unroll
                for (int r = 0; r < 4; r++) {
                    int l = lh * 32 + fm * 16 + (lane >> 4) * 4 + r;
                    int m = mq * 64 + fn * 16 + lr;
                    sQf[l * 264 + m] = f2h(__expf(ap[fn][r] - snsq[l]) * 0.0625f);
                }
        }
        if (st < 3) { // issue next Q load; lands under norm+attn+epilogue
            gQ += 131072;
            vh = *(const u16x8*)(QK + gQ);
        }
        __syncthreads();
        { // norm
            int l = tid >> 3, m0 = (tid & 7) * 32;
            float s = 0.f;
#pragma unroll
            for (int j4 = 0; j4 < 4; j4++) {
                u16x8 qv = *(const u16x8*)&sQf[l * 264 + m0 + j4 * 8];
#pragma unroll
                for (int j = 0; j < 8; j++) s += h2f(qv[j]) * sKs[m0 + j4 * 8 + j];
            }
            s += __shfl_xor(s, 1); s += __shfl_xor(s, 2); s += __shfl_xor(s, 4);
            if ((tid & 7) == 0) snorm[l] = s;
        }
        f32x4 aa[2];
#pragma unroll
        for (int fn = 0; fn < 2; fn++)
#pragma unroll
            for (int r = 0; r < 4; r++) aa[fn][r] = 0.f;
#pragma unroll
        for (int ks = 0; ks < 8; ks++) {
            f16x8 a = *(const f16x8*)&sQf[(af * 16 + lr) * 264 + ks * 32 + lk];
            aa[0] = mfma16h(a, kvb[0][ks], aa[0]);
            aa[1] = mfma16h(a, kvb[1][ks], aa[1]);
        }
        __syncthreads();
        float* ep = (float*)sQf; // [64][68]
#pragma unroll
        for (int fn = 0; fn < 2; fn++)
#pragma unroll
            for (int r = 0; r < 4; r++) {
                int l = af * 16 + (lane >> 4) * 4 + r;
                int d = ad * 32 + fn * 16 + lr;
                ep[l * 68 + d] = aa[fn][r];
            }
        __syncthreads();
        {
            int l = tid >> 3, d0 = (tid & 7) * 8;
            float inv = 1.0f / fmaxf(snorm[l], 6.25e-8f);
            u16x8 o;
#pragma unroll
            for (int j = 0; j < 8; j++) o[j] = f2h(ep[l * 68 + d0 + j] * inv);
            *(u16x8*)(attn + ((size_t)(b * Ll + l0 + l)) * 1024 + h * 64 + d0) = o;
        }
    }
}

extern "C" void kernel_launch(void* const* d_in, const int* in_sizes, int n_in,
                              void* d_out, int out_size, void* d_ws, size_t ws_size,
                              hipStream_t stream) {
    (void)in_sizes; (void)n_in; (void)out_size; (void)ws_size;
    const float* x  = (const float*)d_in[0];
    const float* Wq = (const float*)d_in[1];
    const float* Wk = (const float*)d_in[2];
    const float* Wv = (const float*)d_in[3];
    const float* Wo = (const float*)d_in[4];
    const float* bo = (const float*)d_in[5];
    const float* om = (const float*)d_in[6];

    char* w = (char*)d_ws;
    size_t o = 0;
    auto take = [&](size_t n) { char* p = w + o; o += n; return p; };
    u16* QK  = (u16*)take(67108864);   // [16384][2048] fp16: Q | K
    u16* Vb  = (u16*)take(33554432);   // [16384][1024] fp16
    u16* xh  = (u16*)take(33554432);   // x fp16
    u16* Wc  = (u16*)take(8388608);    // Wq|Wk|Wv|Wo fp16 [4096][1024]
    u16* wt  = (u16*)take(32768);      // omega^T scaled fp16 [256][64]
    float* KVacc = (float*)take(67108864); // 16 slabs x [64 bh][256 m][64 d]
    float* Ksum  = (float*)take(1048576);  // 16 slabs x [64 bh][256 m]
    float* KsumR = (float*)take(65536);    // [64 bh][256 m]
    u16* KVt = (u16*)take(2097152);        // [64 bh][64 d][256 m]
    u16* Wof  = Wc + 3145728;
    u16* attn = Vb; // alias: V dead after k_phik_kv

    k_prep<<<20544, 256, 0, stream>>>(x, Wq, Wk, Wv, Wo, om, xh, Wc, wt);
    k_gemm_qkv<<<dim3(12, 64), 512, 0, stream>>>(xh, Wc, QK, Vb);
    k_phik_kv<<<dim3(16, 64), 256, 0, stream>>>(QK, wt, Vb, KVacc, Ksum);
    k_kvt<<<16448, 256, 0, stream>>>(KVacc, Ksum, KVt, KsumR);
    k_phiq_attn<<<dim3(16, 64), 512, 0, stream>>>(QK, wt, KVt, KsumR, attn);
    k_gemm_out<<<dim3(4, 64), 512, 0, stream>>>(attn, Wof, bo, (float*)d_out);
}

// Round 11
// 362.528 us; speedup vs baseline: 1.0406x; 1.0406x over previous
//
#include <hip/hip_runtime.h>

typedef unsigned short u16;
typedef __attribute__((ext_vector_type(4))) float f32x4;
typedef _Float16 f16x8 __attribute__((ext_vector_type(8)));
typedef __attribute__((ext_vector_type(4))) u16   u16x4;
typedef __attribute__((ext_vector_type(8))) u16   u16x8;

#define DEV static __device__ __forceinline__

constexpr int Ll = 4096;

DEV float h2f(u16 v) { _Float16 h; __builtin_memcpy(&h, &v, 2); return (float)h; }
DEV u16 f2h(float f) { _Float16 h = (_Float16)f; u16 u; __builtin_memcpy(&u, &h, 2); return u; }

DEV f32x4 mfma16h(f16x8 a, f16x8 b, f32x4 c) {
    return __builtin_amdgcn_mfma_f32_16x16x32_f16(a, b, c, 0, 0, 0);
}

#if defined(__has_builtin)
#if __has_builtin(__builtin_amdgcn_global_load_lds)
#define HAS_GLLDS 1
#endif
#endif
#ifndef HAS_GLLDS
#define HAS_GLLDS 0
#endif

#define SBAR()  __builtin_amdgcn_s_barrier()
#define SCHED() __builtin_amdgcn_sched_barrier(0)
#define LGKM0() asm volatile("s_waitcnt lgkmcnt(0)" ::: "memory")

// ---- m201-style stage: one region (256 rows x 32 cols fp16 = 16KB) = 2 gload units.
#if HAS_GLLDS
#define STG2(BUF, REG, SRC, ROWBASE, TK, KS)                                         \
  { _Pragma("unroll") for (int u_ = 0; u_ < 2; u_++) {                               \
      int row_ = u_ * 128 + wave * 16 + (lane >> 2);                                 \
      int c_ = lane & 3;                                                             \
      const u16* gp_ = (SRC) + (size_t)((ROWBASE) + row_) * 1024 + (TK) * 64         \
                        + (KS) * 32 + ((c_ ^ ((row_ >> 1) & 3)) * 8);                \
      __builtin_amdgcn_global_load_lds(                                              \
        (const __attribute__((address_space(1))) unsigned int*)gp_,                  \
        (__attribute__((address_space(3))) unsigned int*)(sm + (BUF) * 32768 +       \
          (REG) * 8192 + (u_ * 512 + wave * 64) * 8), 16, 0, 0); } }
#else
#define STG2(BUF, REG, SRC, ROWBASE, TK, KS)                                         \
  { _Pragma("unroll") for (int u_ = 0; u_ < 2; u_++) {                               \
      int row_ = u_ * 128 + wave * 16 + (lane >> 2);                                 \
      int c_ = lane & 3;                                                             \
      const u16* gp_ = (SRC) + (size_t)((ROWBASE) + row_) * 1024 + (TK) * 64         \
                        + (KS) * 32 + ((c_ ^ ((row_ >> 1) & 3)) * 8);                \
      *(u16x8*)(sm + (BUF) * 32768 + (REG) * 8192 + (u_ * 512 + wave * 64 + lane) * 8) \
          = *(const u16x8*)gp_; } }
#endif

// ---- 256^2 staging for k_gemm_out: [256][32] tile, 4 units of 8KB ----
#if HAS_GLLDS
#define STG(BUF, U, SRC, ROWBASE, KK)                                                \
  { int rl_ = wave * 16 + (lane >> 2);                                               \
    int c_ = lane & 3;                                                               \
    int grow_ = (((U) & 1) * 128) + rl_;                                             \
    const u16* gp_ = (SRC) + (size_t)((ROWBASE) + grow_) * 1024 + (KK)               \
                     + ((c_ ^ ((rl_ >> 1) & 3)) * 8);                                \
    __builtin_amdgcn_global_load_lds(                                                \
        (const __attribute__((address_space(1))) unsigned int*)gp_,                  \
        (__attribute__((address_space(3))) unsigned int*)(sm + (BUF) * 16384 +       \
            (U) * 4096 + wave * 512), 16, 0, 0); }
#else
#define STG(BUF, U, SRC, ROWBASE, KK)                                                \
  { int rl_ = wave * 16 + (lane >> 2);                                               \
    int c_ = lane & 3;                                                               \
    int grow_ = (((U) & 1) * 128) + rl_;                                             \
    const u16* gp_ = (SRC) + (size_t)((ROWBASE) + grow_) * 1024 + (KK)               \
                     + ((c_ ^ ((rl_ >> 1) & 3)) * 8);                                \
    *(u16x8*)(sm + (BUF) * 16384 + (U) * 4096 + wave * 512 + lane * 8)               \
        = *(const u16x8*)gp_; }
#endif

// ---------------- merged prep: x, Wq|Wk|Wv|Wo, omega ----------------
__global__ __launch_bounds__(256) void k_prep(
    const float* __restrict__ x, const float* __restrict__ Wq, const float* __restrict__ Wk,
    const float* __restrict__ Wv, const float* __restrict__ Wo, const float* __restrict__ om,
    u16* __restrict__ xh, u16* __restrict__ Wc, u16* __restrict__ wtp) {
    int bx = blockIdx.x, tid = threadIdx.x;
    if (bx < 16384) {
        size_t i = ((size_t)bx * 256 + tid) * 4;
        f32x4 v = *(const f32x4*)(x + i);
        u16x4 h;
#pragma unroll
        for (int j = 0; j < 4; j++) h[j] = f2h(v[j]);
        *(u16x4*)(xh + i) = h;
    } else if (bx < 20480) {
        int wsel = (bx - 16384) >> 10;
        const float* src = (wsel == 0) ? Wq : (wsel == 1) ? Wk : (wsel == 2) ? Wv : Wo;
        size_t i = ((size_t)((bx - 16384) & 1023) * 256 + tid) * 4;
        f32x4 v = *(const f32x4*)(src + i);
        u16x4 h;
#pragma unroll
        for (int j = 0; j < 4; j++) h[j] = f2h(v[j]);
        *(u16x4*)(Wc + (size_t)wsel * 1048576 + i) = h;
    } else {
        int i = (bx - 20480) * 256 + tid; // 16384
        int m = i >> 6, d = i & 63;
        wtp[i] = f2h(om[d * 256 + m] * 0.35355339059327373f);
    }
}

// ---------------- QKV GEMM: 256x256, BK=64, 8-phase, counted vmcnt (r8, frozen) ----------------
__global__ __launch_bounds__(512, 1) void k_gemm_qkv(
    const u16* __restrict__ Ax, const u16* __restrict__ Bw,
    u16* __restrict__ QK, u16* __restrict__ Vb) {
    __shared__ __align__(16) u16 sm[65536]; // 128 KB
    const int tid = threadIdx.x, wave = tid >> 6, lane = tid & 63;
    const int lr = lane & 15, lkq = lane >> 4;
    const int wr = wave >> 2, wc = wave & 3;
    const int m0 = blockIdx.y * 256, n0 = blockIdx.x * 256;
    const int sec = n0 >> 10;

    const int arow = wr * 128 + lr;
    const int aBase = arow * 32 + ((lkq ^ ((arow >> 1) & 3)) * 8);
    const int brow = wc * 64 + lr;
    const int bBase = 16384 + brow * 32 + ((lkq ^ ((brow >> 1) & 3)) * 8);

    f32x4 acc[8][4];
#pragma unroll
    for (int i = 0; i < 8; i++)
#pragma unroll
        for (int j = 0; j < 4; j++)
#pragma unroll
            for (int r = 0; r < 4; r++) acc[i][j][r] = 0.f;

    STG2(0, 0, Ax, m0, 0, 0)
    STG2(0, 2, Bw, n0, 0, 0)
    STG2(0, 1, Ax, m0, 0, 1)
    STG2(0, 3, Bw, n0, 0, 1)
    asm volatile("s_waitcnt vmcnt(4)" ::: "memory");
    SCHED(); SBAR(); SCHED();

    f16x8 bfr[2][4], afr[4];
    for (int t = 0; t < 16; ++t) {
        const u16* bp = sm + (t & 1) * 32768;
        const int nb = (t + 1) & 1;
        const bool st = t < 15;
#pragma unroll
        for (int f = 0; f < 4; f++) afr[f] = *(const f16x8*)&bp[aBase + f * 512];
#pragma unroll
        for (int j = 0; j < 4; j++) bfr[0][j] = *(const f16x8*)&bp[bBase + j * 512];
        if (st) STG2(nb, 0, Ax, m0, t + 1, 0)
        SBAR(); LGKM0(); SCHED();
        __builtin_amdgcn_s_setprio(1);
#pragma unroll
        for (int i = 0; i < 4; i++)
#pragma unroll
            for (int j = 0; j < 4; j++)
                acc[i][j] = mfma16h(afr[i], bfr[0][j], acc[i][j]);
        __builtin_amdgcn_s_setprio(0);
        SCHED();
        if (st) { asm volatile("s_waitcnt vmcnt(2)" ::: "memory"); }
        else    { asm volatile("s_waitcnt vmcnt(0)" ::: "memory"); }
        SCHED(); SBAR(); SCHED();
#pragma unroll
        for (int f = 0; f < 4; f++) afr[f] = *(const f16x8*)&bp[aBase + 8192 + f * 512];
#pragma unroll
        for (int j = 0; j < 4; j++) bfr[1][j] = *(const f16x8*)&bp[bBase + 8192 + j * 512];
        if (st) STG2(nb, 2, Bw, n0, t + 1, 0)
        SBAR(); LGKM0(); SCHED();
        __builtin_amdgcn_s_setprio(1);
#pragma unroll
        for (int i = 0; i < 4; i++)
#pragma unroll
            for (int j = 0; j < 4; j++)
                acc[i][j] = mfma16h(afr[i], bfr[1][j], acc[i][j]);
        __builtin_amdgcn_s_setprio(0);
        SCHED(); SBAR(); SCHED();
#pragma unroll
        for (int f = 0; f < 4; f++) afr[f] = *(const f16x8*)&bp[aBase + 2048 + f * 512];
        if (st) STG2(nb, 1, Ax, m0, t + 1, 1)
        SBAR(); LGKM0(); SCHED();
        __builtin_amdgcn_s_setprio(1);
#pragma unroll
        for (int i = 0; i < 4; i++)
#pragma unroll
            for (int j = 0; j < 4; j++)
                acc[4 + i][j] = mfma16h(afr[i], bfr[0][j], acc[4 + i][j]);
        __builtin_amdgcn_s_setprio(0);
        SCHED(); SBAR(); SCHED();
#pragma unroll
        for (int f = 0; f < 4; f++) afr[f] = *(const f16x8*)&bp[aBase + 8192 + 2048 + f * 512];
        if (st) STG2(nb, 3, Bw, n0, t + 1, 1)
        SBAR(); LGKM0(); SCHED();
        __builtin_amdgcn_s_setprio(1);
#pragma unroll
        for (int i = 0; i < 4; i++)
#pragma unroll
            for (int j = 0; j < 4; j++)
                acc[4 + i][j] = mfma16h(afr[i], bfr[1][j], acc[4 + i][j]);
        __builtin_amdgcn_s_setprio(0);
        SCHED();
        if (st) { asm volatile("s_waitcnt vmcnt(4)" ::: "memory"); }
        SCHED(); SBAR(); SCHED();
    }

    float* ep = (float*)sm; // [32][264]
    for (int g = 0; g < 8; g++) {
        __syncthreads();
        if (wr == (g >> 2)) {
#pragma unroll
            for (int fi = 0; fi < 2; fi++) {
                int fm = (g & 3) * 2 + fi;
#pragma unroll
                for (int fn = 0; fn < 4; fn++)
#pragma unroll
                    for (int r = 0; r < 4; r++)
                        ep[(fi * 16 + (lane >> 4) * 4 + r) * 264 + wc * 64 + fn * 16 + lr] = acc[fm][fn][r];
            }
        }
        __syncthreads();
        int row = tid >> 4, c0 = (tid & 15) * 16;
        int grow = m0 + g * 32 + row;
        u16x8 h0, h1;
#pragma unroll
        for (int j = 0; j < 8; j++) {
            h0[j] = f2h(ep[row * 264 + c0 + j]);
            h1[j] = f2h(ep[row * 264 + c0 + 8 + j]);
        }
        if (sec < 2) {
            size_t o = (size_t)grow * 2048 + (n0 + c0);
            *(u16x8*)(QK + o) = h0; *(u16x8*)(QK + o + 8) = h1;
        } else {
            size_t o = (size_t)grow * 1024 + (n0 - 2048 + c0);
            *(u16x8*)(Vb + o) = h0; *(u16x8*)(Vb + o + 8) = h1;
        }
    }
}

// ---------------- final GEMM: attn @ Wo^T + bo -> f32 out (r7 2-phase, 2 blocks/CU) ----------------
__global__ __launch_bounds__(512, 2) void k_gemm_out(
    const u16* __restrict__ Ab, const u16* __restrict__ Bw,
    const float* __restrict__ bias, float* __restrict__ outp) {
    __shared__ __align__(16) u16 sm[32768];
    const int tid = threadIdx.x, wave = tid >> 6, lane = tid & 63;
    const int lr = lane & 15, lkq = lane >> 4;
    const int wr = wave >> 2, wc = wave & 3;
    const int m0 = blockIdx.y * 256, n0 = blockIdx.x * 256;

    int aoff[8], boff[4];
#pragma unroll
    for (int f = 0; f < 8; f++) {
        int row = wr * 128 + f * 16 + lr;
        aoff[f] = row * 32 + ((lkq ^ ((row >> 1) & 3)) * 8);
    }
#pragma unroll
    for (int f = 0; f < 4; f++) {
        int row = wc * 64 + f * 16 + lr;
        boff[f] = row * 32 + ((lkq ^ ((row >> 1) & 3)) * 8);
    }

    f32x4 acc[8][4];
#pragma unroll
    for (int i = 0; i < 8; i++)
#pragma unroll
        for (int j = 0; j < 4; j++)
#pragma unroll
            for (int r = 0; r < 4; r++) acc[i][j][r] = 0.f;

    STG(0, 0, Ab, m0, 0) STG(0, 1, Ab, m0, 0)
    STG(0, 2, Bw, n0, 0) STG(0, 3, Bw, n0, 0)
    asm volatile("s_waitcnt vmcnt(0)" ::: "memory");
    SCHED(); SBAR(); SCHED();

    int cb = 0;
    for (int t = 0; t < 32; ++t) {
        const u16* Abase = sm + cb * 16384;
        const u16* Bbase = Abase + 8192;
        f16x8 afr[4], bfr[4];
#pragma unroll
        for (int f = 0; f < 4; f++) bfr[f] = *(const f16x8*)&Bbase[boff[f]];
#pragma unroll
        for (int f = 0; f < 4; f++) afr[f] = *(const f16x8*)&Abase[aoff[f]];
        if (t < 31) {
            int kk = (t + 1) * 32;
            STG(cb ^ 1, 0, Ab, m0, kk) STG(cb ^ 1, 1, Ab, m0, kk)
            STG(cb ^ 1, 2, Bw, n0, kk) STG(cb ^ 1, 3, Bw, n0, kk)
        }
        SCHED(); SBAR(); LGKM0(); SCHED();
        __builtin_amdgcn_s_setprio(1);
#pragma unroll
        for (int i = 0; i < 4; i++)
#pragma unroll
            for (int j = 0; j < 4; j++)
                acc[i][j] = mfma16h(afr[i], bfr[j], acc[i][j]);
        __builtin_amdgcn_s_setprio(0);
        SCHED(); SBAR(); SCHED();
#pragma unroll
        for (int f = 0; f < 4; f++) afr[f] = *(const f16x8*)&Abase[aoff[4 + f]];
        SCHED(); SBAR(); LGKM0(); SCHED();
        __builtin_amdgcn_s_setprio(1);
#pragma unroll
        for (int i = 0; i < 4; i++)
#pragma unroll
            for (int j = 0; j < 4; j++)
                acc[4 + i][j] = mfma16h(afr[i], bfr[j], acc[4 + i][j]);
        __builtin_amdgcn_s_setprio(0);
        asm volatile("s_waitcnt vmcnt(0)" ::: "memory");
        SCHED(); SBAR(); SCHED();
        cb ^= 1;
    }

    float* ep = (float*)sm; // [32][264]
    for (int g = 0; g < 8; g++) {
        __syncthreads();
        if (wr == (g >> 2)) {
#pragma unroll
            for (int fi = 0; fi < 2; fi++) {
                int fm = (g & 3) * 2 + fi;
#pragma unroll
                for (int fn = 0; fn < 4; fn++)
#pragma unroll
                    for (int r = 0; r < 4; r++)
                        ep[(fi * 16 + (lane >> 4) * 4 + r) * 264 + wc * 64 + fn * 16 + lr] = acc[fm][fn][r];
            }
        }
        __syncthreads();
        int row = tid >> 4, c0 = (tid & 15) * 16;
        int grow = m0 + g * 32 + row;
        float vv[16];
#pragma unroll
        for (int j = 0; j < 16; j++) vv[j] = ep[row * 264 + c0 + j] + bias[n0 + c0 + j];
#pragma unroll
        for (int p = 0; p < 4; p++) {
            f32x4 tv;
#pragma unroll
            for (int q = 0; q < 4; q++) tv[q] = vv[p * 4 + q];
            *(f32x4*)(outp + (size_t)grow * 1024 + n0 + c0 + p * 4) = tv;
        }
    }
}

// ---------------- fused phi(K) + KV + Ksum: 8 slabs, reg prefetch, setprio ----------------
__global__ __launch_bounds__(256) void k_phik_kv(
    const u16* __restrict__ QK, const u16* __restrict__ wt,
    const u16* __restrict__ Vb, float* __restrict__ KVacc, float* __restrict__ Ksum) {
    __shared__ __align__(16) u16 sKh[64 * 72];
    __shared__ __align__(16) u16 sVt[64 * 72];
    __shared__ __align__(16) u16 sKfT[256 * 72];
    __shared__ float snsq[64];
    const int tid = threadIdx.x, wave = tid >> 6, lane = tid & 63;
    const int lr = lane & 15, lk = (lane >> 4) * 8;
    const int kc = blockIdx.x, bh = blockIdx.y;
    const int b = bh >> 4, h = bh & 15;

    f16x8 wb[4][2];
#pragma unroll
    for (int fn = 0; fn < 4; fn++)
#pragma unroll
        for (int ks = 0; ks < 2; ks++)
            wb[fn][ks] = *(const f16x8*)(wt + (size_t)(wave * 64 + fn * 16 + lr) * 64 + ks * 32 + lk);

    f32x4 akv[4][4];
#pragma unroll
    for (int i = 0; i < 4; i++)
#pragma unroll
        for (int j = 0; j < 4; j++)
#pragma unroll
            for (int r = 0; r < 4; r++) akv[i][j][r] = 0.f;
    float ksm[4] = {0.f, 0.f, 0.f, 0.f};

    // prefetch regs for iteration 0
    const int rowS = tid >> 2, cS = (tid & 3) * 16;
    size_t gK = ((size_t)(b * Ll + kc * 512 + rowS)) * 2048 + 1024 + h * 64 + cS;
    size_t gV = ((size_t)(b * Ll + kc * 512 + rowS)) * 1024 + h * 64 + cS;
    u16x8 kh0 = *(const u16x8*)(QK + gK);
    u16x8 kh1 = *(const u16x8*)(QK + gK + 8);
    u16x8 vv0 = *(const u16x8*)(Vb + gV);
    u16x8 vv1 = *(const u16x8*)(Vb + gV + 8);

    for (int it = 0; it < 8; it++) {
        __syncthreads();
        { // write K stage + nsq from regs
            *(u16x8*)&sKh[rowS * 72 + cS]     = kh0;
            *(u16x8*)&sKh[rowS * 72 + cS + 8] = kh1;
            float s = 0.f;
#pragma unroll
            for (int j = 0; j < 8; j++) {
                float a = h2f(kh0[j]); s += a * a;
                float c = h2f(kh1[j]); s += c * c;
            }
            s += __shfl_xor(s, 1); s += __shfl_xor(s, 2);
            if ((tid & 3) == 0) snsq[rowS] = s * 0.0625f;
        }
        { // write V transposed from regs
#pragma unroll
            for (int j = 0; j < 8; j++) {
                sVt[(cS + j) * 72 + rowS]     = vv0[j];
                sVt[(cS + 8 + j) * 72 + rowS] = vv1[j];
            }
        }
        __syncthreads();
        if (it < 7) { // issue next-iteration loads; land under MFMA phases
            gK += 131072; gV += 65536;
            kh0 = *(const u16x8*)(QK + gK);
            kh1 = *(const u16x8*)(QK + gK + 8);
            vv0 = *(const u16x8*)(Vb + gV);
            vv1 = *(const u16x8*)(Vb + gV + 8);
        }
#pragma unroll
        for (int fm = 0; fm < 4; fm++) {
            f32x4 ap[4];
#pragma unroll
            for (int fn = 0; fn < 4; fn++)
#pragma unroll
                for (int r = 0; r < 4; r++) ap[fn][r] = 0.f;
            __builtin_amdgcn_s_setprio(1);
#pragma unroll
            for (int ks = 0; ks < 2; ks++) {
                f16x8 aH = *(const f16x8*)&sKh[(fm * 16 + lr) * 72 + ks * 32 + lk];
#pragma unroll
                for (int fn = 0; fn < 4; fn++)
                    ap[fn] = mfma16h(aH, wb[fn][ks], ap[fn]);
            }
            __builtin_amdgcn_s_setprio(0);
#pragma unroll
            for (int fn = 0; fn < 4; fn++) {
                u16x4 pk;
#pragma unroll
                for (int r = 0; r < 4; r++) {
                    float ns = snsq[fm * 16 + (lane >> 4) * 4 + r];
                    float val = __expf(ap[fn][r] - ns) * 0.00390625f; // 1/256
                    ksm[fn] += val;
                    pk[r] = f2h(val);
                }
                *(u16x4*)&sKfT[(wave * 64 + fn * 16 + lr) * 72 + fm * 16 + (lane >> 4) * 4] = pk;
            }
        }
        __builtin_amdgcn_s_setprio(1);
#pragma unroll
        for (int ks = 0; ks < 2; ks++) {
            f16x8 a4[4], b4[4];
#pragma unroll
            for (int f = 0; f < 4; f++) {
                a4[f] = *(const f16x8*)&sKfT[(wave * 64 + f * 16 + lr) * 72 + ks * 32 + lk];
                b4[f] = *(const f16x8*)&sVt[(f * 16 + lr) * 72 + ks * 32 + lk];
            }
#pragma unroll
            for (int fm = 0; fm < 4; fm++)
#pragma unroll
                for (int fn = 0; fn < 4; fn++)
                    akv[fm][fn] = mfma16h(a4[fm], b4[fn], akv[fm][fn]);
        }
        __builtin_amdgcn_s_setprio(0);
    }
    // owned-slab stores (no atomics); 8 slabs
    const size_t base = ((size_t)(kc * 64 + bh)) << 14;
#pragma unroll
    for (int fm = 0; fm < 4; fm++)
#pragma unroll
        for (int fn = 0; fn < 4; fn++)
#pragma unroll
            for (int r = 0; r < 4; r++) {
                int m = wave * 64 + fm * 16 + (lane >> 4) * 4 + r;
                int d = fn * 16 + lr;
                KVacc[base + m * 64 + d] = akv[fm][fn][r];
            }
#pragma unroll
    for (int fn = 0; fn < 4; fn++) {
        ksm[fn] += __shfl_xor(ksm[fn], 16);
        ksm[fn] += __shfl_xor(ksm[fn], 32);
    }
    if (lane < 16) {
#pragma unroll
        for (int fn = 0; fn < 4; fn++)
            Ksum[(kc * 64 + bh) * 256 + wave * 64 + fn * 16 + lane] = ksm[fn];
    }
}

// ---------------- slab reduce: KVt[bh][d][m] = fp16(sum_kc KVacc), KsumR = sum_kc Ksum ----------------
__global__ __launch_bounds__(256) void k_kvt(const float* __restrict__ KVacc,
                                             const float* __restrict__ Ksum,
                                             u16* __restrict__ KVt, float* __restrict__ KsumR) {
    int i = blockIdx.x * 256 + threadIdx.x;
    if (blockIdx.x < 16384) {
        int bh = i >> 14, m = (i >> 6) & 255, d = i & 63;
        float s = 0.f;
#pragma unroll
        for (int kc = 0; kc < 8; kc++)
            s += KVacc[(((size_t)(kc * 64 + bh)) << 14) + m * 64 + d];
        KVt[((size_t)bh << 14) + d * 256 + m] = f2h(s);
    } else {
        int j = i - 4194304; // bh*256+m, 16384 total
        int bh = j >> 8, m = j & 255;
        float s = 0.f;
#pragma unroll
        for (int kc = 0; kc < 8; kc++)
            s += Ksum[(kc * 64 + bh) * 256 + m];
        KsumR[j] = s;
    }
}

// ---------------- fused phi(Q) + norm + attn: 4 subtiles/block, Q prefetch, setprio ----------------
__global__ __launch_bounds__(512) void k_phiq_attn(
    const u16* __restrict__ QK, const u16* __restrict__ wt,
    const u16* __restrict__ KVt, const float* __restrict__ Ksum,
    u16* __restrict__ attn) {
    __shared__ __align__(16) u16 sQh[64 * 72];
    __shared__ __align__(16) u16 sQf[64 * 264];
    __shared__ float sKs[256];
    __shared__ float snsq[64];
    __shared__ float snorm[64];
    const int tid = threadIdx.x, wave = tid >> 6, lane = tid & 63;
    const int lr = lane & 15, lk = (lane >> 4) * 8;
    const int bh = blockIdx.y, b = bh >> 4, h = bh & 15;
    const int mq = wave & 3;
    const int lh = wave >> 2;
    const int af = wave & 3;
    const int ad = wave >> 2;

    f16x8 wb[4][2];
#pragma unroll
    for (int fn = 0; fn < 4; fn++)
#pragma unroll
        for (int ks = 0; ks < 2; ks++)
            wb[fn][ks] = *(const f16x8*)(wt + (size_t)(mq * 64 + fn * 16 + lr) * 64 + ks * 32 + lk);
    f16x8 kvb[2][8];
#pragma unroll
    for (int fn = 0; fn < 2; fn++)
#pragma unroll
        for (int ks = 0; ks < 8; ks++)
            kvb[fn][ks] = *(const f16x8*)(KVt + ((size_t)bh << 14) +
                                          (size_t)(ad * 32 + fn * 16 + lr) * 256 + ks * 32 + lk);
    if (tid < 256) sKs[tid] = Ksum[bh * 256 + tid];

    // Q prefetch for st=0
    const int rowQ = tid >> 3, cQ = (tid & 7) * 8;
    size_t gQ = ((size_t)(b * Ll + blockIdx.x * 256 + rowQ)) * 2048 + h * 64 + cQ;
    u16x8 vh = *(const u16x8*)(QK + gQ);

    for (int st = 0; st < 4; st++) {
        const int l0 = blockIdx.x * 256 + st * 64;
        __syncthreads();
        { // stage Q + nsq from regs
            *(u16x8*)&sQh[rowQ * 72 + cQ] = vh;
            float s = 0.f;
#pragma unroll
            for (int j = 0; j < 8; j++) { float a = h2f(vh[j]); s += a * a; }
            s += __shfl_xor(s, 1); s += __shfl_xor(s, 2); s += __shfl_xor(s, 4);
            if ((tid & 7) == 0) snsq[rowQ] = s * 0.0625f;
        }
        __syncthreads();
#pragma unroll
        for (int fm = 0; fm < 2; fm++) {
            f32x4 ap[4];
#pragma unroll
            for (int fn = 0; fn < 4; fn++)
#pragma unroll
                for (int r = 0; r < 4; r++) ap[fn][r] = 0.f;
            __builtin_amdgcn_s_setprio(1);
#pragma unroll
            for (int ks = 0; ks < 2; ks++) {
                f16x8 aH = *(const f16x8*)&sQh[(lh * 32 + fm * 16 + lr) * 72 + ks * 32 + lk];
#pragma unroll
                for (int fn = 0; fn < 4; fn++)
                    ap[fn] = mfma16h(aH, wb[fn][ks], ap[fn]);
            }
            __builtin_amdgcn_s_setprio(0);
#pragma unroll
            for (int fn = 0; fn < 4; fn++)
#pragma unroll
                for (int r = 0; r < 4; r++) {
                    int l = lh * 32 + fm * 16 + (lane >> 4) * 4 + r;
                    int m = mq * 64 + fn * 16 + lr;
                    sQf[l * 264 + m] = f2h(__expf(ap[fn][r] - snsq[l]) * 0.0625f);
                }
        }
        if (st < 3) { // issue next Q load; lands under norm+attn+epilogue
            gQ += 131072;
            vh = *(const u16x8*)(QK + gQ);
        }
        __syncthreads();
        { // norm
            int l = tid >> 3, m0 = (tid & 7) * 32;
            float s = 0.f;
#pragma unroll
            for (int j4 = 0; j4 < 4; j4++) {
                u16x8 qv = *(const u16x8*)&sQf[l * 264 + m0 + j4 * 8];
#pragma unroll
                for (int j = 0; j < 8; j++) s += h2f(qv[j]) * sKs[m0 + j4 * 8 + j];
            }
            s += __shfl_xor(s, 1); s += __shfl_xor(s, 2); s += __shfl_xor(s, 4);
            if ((tid & 7) == 0) snorm[l] = s;
        }
        f32x4 aa[2];
#pragma unroll
        for (int fn = 0; fn < 2; fn++)
#pragma unroll
            for (int r = 0; r < 4; r++) aa[fn][r] = 0.f;
        __builtin_amdgcn_s_setprio(1);
#pragma unroll
        for (int ks = 0; ks < 8; ks++) {
            f16x8 a = *(const f16x8*)&sQf[(af * 16 + lr) * 264 + ks * 32 + lk];
            aa[0] = mfma16h(a, kvb[0][ks], aa[0]);
            aa[1] = mfma16h(a, kvb[1][ks], aa[1]);
        }
        __builtin_amdgcn_s_setprio(0);
        __syncthreads();
        float* ep = (float*)sQf; // [64][68]
#pragma unroll
        for (int fn = 0; fn < 2; fn++)
#pragma unroll
            for (int r = 0; r < 4; r++) {
                int l = af * 16 + (lane >> 4) * 4 + r;
                int d = ad * 32 + fn * 16 + lr;
                ep[l * 68 + d] = aa[fn][r];
            }
        __syncthreads();
        {
            int l = tid >> 3, d0 = (tid & 7) * 8;
            float inv = 1.0f / fmaxf(snorm[l], 6.25e-8f);
            u16x8 o;
#pragma unroll
            for (int j = 0; j < 8; j++) o[j] = f2h(ep[l * 68 + d0 + j] * inv);
            *(u16x8*)(attn + ((size_t)(b * Ll + l0 + l)) * 1024 + h * 64 + d0) = o;
        }
    }
}

extern "C" void kernel_launch(void* const* d_in, const int* in_sizes, int n_in,
                              void* d_out, int out_size, void* d_ws, size_t ws_size,
                              hipStream_t stream) {
    (void)in_sizes; (void)n_in; (void)out_size; (void)ws_size;
    const float* x  = (const float*)d_in[0];
    const float* Wq = (const float*)d_in[1];
    const float* Wk = (const float*)d_in[2];
    const float* Wv = (const float*)d_in[3];
    const float* Wo = (const float*)d_in[4];
    const float* bo = (const float*)d_in[5];
    const float* om = (const float*)d_in[6];

    char* w = (char*)d_ws;
    size_t o = 0;
    auto take = [&](size_t n) { char* p = w + o; o += n; return p; };
    u16* QK  = (u16*)take(67108864);   // [16384][2048] fp16: Q | K
    u16* Vb  = (u16*)take(33554432);   // [16384][1024] fp16
    u16* xh  = (u16*)take(33554432);   // x fp16
    u16* Wc  = (u16*)take(8388608);    // Wq|Wk|Wv|Wo fp16 [4096][1024]
    u16* wt  = (u16*)take(32768);      // omega^T scaled fp16 [256][64]
    float* KVacc = (float*)take(33554432); // 8 slabs x [64 bh][256 m][64 d]
    float* Ksum  = (float*)take(524288);   // 8 slabs x [64 bh][256 m]
    float* KsumR = (float*)take(65536);    // [64 bh][256 m]
    u16* KVt = (u16*)take(2097152);        // [64 bh][64 d][256 m]
    u16* Wof  = Wc + 3145728;
    u16* attn = Vb; // alias: V dead after k_phik_kv

    k_prep<<<20544, 256, 0, stream>>>(x, Wq, Wk, Wv, Wo, om, xh, Wc, wt);
    k_gemm_qkv<<<dim3(12, 64), 512, 0, stream>>>(xh, Wc, QK, Vb);
    k_phik_kv<<<dim3(8, 64), 256, 0, stream>>>(QK, wt, Vb, KVacc, Ksum);
    k_kvt<<<16448, 256, 0, stream>>>(KVacc, Ksum, KVt, KsumR);
    k_phiq_attn<<<dim3(16, 64), 512, 0, stream>>>(QK, wt, KVt, KsumR, attn);
    k_gemm_out<<<dim3(4, 64), 512, 0, stream>>>(attn, Wof, bo, (float*)d_out);
}

// Round 12
// 361.639 us; speedup vs baseline: 1.0432x; 1.0025x over previous
//
#include <hip/hip_runtime.h>

typedef unsigned short u16;
typedef __attribute__((ext_vector_type(4))) float f32x4;
typedef _Float16 f16x8 __attribute__((ext_vector_type(8)));
typedef __attribute__((ext_vector_type(4))) u16   u16x4;
typedef __attribute__((ext_vector_type(8))) u16   u16x8;

#define DEV static __device__ __forceinline__

constexpr int Ll = 4096;

DEV float h2f(u16 v) { _Float16 h; __builtin_memcpy(&h, &v, 2); return (float)h; }
DEV u16 f2h(float f) { _Float16 h = (_Float16)f; u16 u; __builtin_memcpy(&u, &h, 2); return u; }

DEV f32x4 mfma16h(f16x8 a, f16x8 b, f32x4 c) {
    return __builtin_amdgcn_mfma_f32_16x16x32_f16(a, b, c, 0, 0, 0);
}

#if defined(__has_builtin)
#if __has_builtin(__builtin_amdgcn_global_load_lds)
#define HAS_GLLDS 1
#endif
#endif
#ifndef HAS_GLLDS
#define HAS_GLLDS 0
#endif

#define SBAR()  __builtin_amdgcn_s_barrier()
#define SCHED() __builtin_amdgcn_sched_barrier(0)
#define LGKM0() asm volatile("s_waitcnt lgkmcnt(0)" ::: "memory")

// ---- m201-style stage: one region (256 rows x 32 cols fp16 = 16KB) = 2 gload units.
#if HAS_GLLDS
#define STG2(BUF, REG, SRC, ROWBASE, TK, KS)                                         \
  { _Pragma("unroll") for (int u_ = 0; u_ < 2; u_++) {                               \
      int row_ = u_ * 128 + wave * 16 + (lane >> 2);                                 \
      int c_ = lane & 3;                                                             \
      const u16* gp_ = (SRC) + (size_t)((ROWBASE) + row_) * 1024 + (TK) * 64         \
                        + (KS) * 32 + ((c_ ^ ((row_ >> 1) & 3)) * 8);                \
      __builtin_amdgcn_global_load_lds(                                              \
        (const __attribute__((address_space(1))) unsigned int*)gp_,                  \
        (__attribute__((address_space(3))) unsigned int*)(sm + (BUF) * 32768 +       \
          (REG) * 8192 + (u_ * 512 + wave * 64) * 8), 16, 0, 0); } }
#else
#define STG2(BUF, REG, SRC, ROWBASE, TK, KS)                                         \
  { _Pragma("unroll") for (int u_ = 0; u_ < 2; u_++) {                               \
      int row_ = u_ * 128 + wave * 16 + (lane >> 2);                                 \
      int c_ = lane & 3;                                                             \
      const u16* gp_ = (SRC) + (size_t)((ROWBASE) + row_) * 1024 + (TK) * 64         \
                        + (KS) * 32 + ((c_ ^ ((row_ >> 1) & 3)) * 8);                \
      *(u16x8*)(sm + (BUF) * 32768 + (REG) * 8192 + (u_ * 512 + wave * 64 + lane) * 8) \
          = *(const u16x8*)gp_; } }
#endif

// ---- 256^2 staging for k_gemm_out: [256][32] tile, 4 units of 8KB ----
#if HAS_GLLDS
#define STG(BUF, U, SRC, ROWBASE, KK)                                                \
  { int rl_ = wave * 16 + (lane >> 2);                                               \
    int c_ = lane & 3;                                                               \
    int grow_ = (((U) & 1) * 128) + rl_;                                             \
    const u16* gp_ = (SRC) + (size_t)((ROWBASE) + grow_) * 1024 + (KK)               \
                     + ((c_ ^ ((rl_ >> 1) & 3)) * 8);                                \
    __builtin_amdgcn_global_load_lds(                                                \
        (const __attribute__((address_space(1))) unsigned int*)gp_,                  \
        (__attribute__((address_space(3))) unsigned int*)(sm + (BUF) * 16384 +       \
            (U) * 4096 + wave * 512), 16, 0, 0); }
#else
#define STG(BUF, U, SRC, ROWBASE, KK)                                                \
  { int rl_ = wave * 16 + (lane >> 2);                                               \
    int c_ = lane & 3;                                                               \
    int grow_ = (((U) & 1) * 128) + rl_;                                             \
    const u16* gp_ = (SRC) + (size_t)((ROWBASE) + grow_) * 1024 + (KK)               \
                     + ((c_ ^ ((rl_ >> 1) & 3)) * 8);                                \
    *(u16x8*)(sm + (BUF) * 16384 + (U) * 4096 + wave * 512 + lane * 8)               \
        = *(const u16x8*)gp_; }
#endif

// ---------------- merged prep: x, Wq|Wk|Wv|Wo, omega ----------------
__global__ __launch_bounds__(256) void k_prep(
    const float* __restrict__ x, const float* __restrict__ Wq, const float* __restrict__ Wk,
    const float* __restrict__ Wv, const float* __restrict__ Wo, const float* __restrict__ om,
    u16* __restrict__ xh, u16* __restrict__ Wc, u16* __restrict__ wtp) {
    int bx = blockIdx.x, tid = threadIdx.x;
    if (bx < 16384) {
        size_t i = ((size_t)bx * 256 + tid) * 4;
        f32x4 v = *(const f32x4*)(x + i);
        u16x4 h;
#pragma unroll
        for (int j = 0; j < 4; j++) h[j] = f2h(v[j]);
        *(u16x4*)(xh + i) = h;
    } else if (bx < 20480) {
        int wsel = (bx - 16384) >> 10;
        const float* src = (wsel == 0) ? Wq : (wsel == 1) ? Wk : (wsel == 2) ? Wv : Wo;
        size_t i = ((size_t)((bx - 16384) & 1023) * 256 + tid) * 4;
        f32x4 v = *(const f32x4*)(src + i);
        u16x4 h;
#pragma unroll
        for (int j = 0; j < 4; j++) h[j] = f2h(v[j]);
        *(u16x4*)(Wc + (size_t)wsel * 1048576 + i) = h;
    } else {
        int i = (bx - 20480) * 256 + tid; // 16384
        int m = i >> 6, d = i & 63;
        wtp[i] = f2h(om[d * 256 + m] * 0.35355339059327373f);
    }
}

// ---------------- QKV GEMM: 256x256, BK=64, 8-phase, counted vmcnt, XCD swizzle ----------------
// 1D grid of 768; work = (bid%8)*96 + bid/8 (bijective): each XCD owns 8 contiguous m-rows.
__global__ __launch_bounds__(512, 1) void k_gemm_qkv(
    const u16* __restrict__ Ax, const u16* __restrict__ Bw,
    u16* __restrict__ QK, u16* __restrict__ Vb) {
    __shared__ __align__(16) u16 sm[65536]; // 128 KB
    const int tid = threadIdx.x, wave = tid >> 6, lane = tid & 63;
    const int lr = lane & 15, lkq = lane >> 4;
    const int wr = wave >> 2, wc = wave & 3;
    const int bid = blockIdx.x;
    const int work = (bid & 7) * 96 + (bid >> 3);
    const int m0 = (work / 12) * 256, n0 = (work % 12) * 256;
    const int sec = n0 >> 10;

    const int arow = wr * 128 + lr;
    const int aBase = arow * 32 + ((lkq ^ ((arow >> 1) & 3)) * 8);
    const int brow = wc * 64 + lr;
    const int bBase = 16384 + brow * 32 + ((lkq ^ ((brow >> 1) & 3)) * 8);

    f32x4 acc[8][4];
#pragma unroll
    for (int i = 0; i < 8; i++)
#pragma unroll
        for (int j = 0; j < 4; j++)
#pragma unroll
            for (int r = 0; r < 4; r++) acc[i][j][r] = 0.f;

    STG2(0, 0, Ax, m0, 0, 0)
    STG2(0, 2, Bw, n0, 0, 0)
    STG2(0, 1, Ax, m0, 0, 1)
    STG2(0, 3, Bw, n0, 0, 1)
    asm volatile("s_waitcnt vmcnt(4)" ::: "memory");
    SCHED(); SBAR(); SCHED();

    f16x8 bfr[2][4], afr[4];
    for (int t = 0; t < 16; ++t) {
        const u16* bp = sm + (t & 1) * 32768;
        const int nb = (t + 1) & 1;
        const bool st = t < 15;
#pragma unroll
        for (int f = 0; f < 4; f++) afr[f] = *(const f16x8*)&bp[aBase + f * 512];
#pragma unroll
        for (int j = 0; j < 4; j++) bfr[0][j] = *(const f16x8*)&bp[bBase + j * 512];
        if (st) STG2(nb, 0, Ax, m0, t + 1, 0)
        SBAR(); LGKM0(); SCHED();
        __builtin_amdgcn_s_setprio(1);
#pragma unroll
        for (int i = 0; i < 4; i++)
#pragma unroll
            for (int j = 0; j < 4; j++)
                acc[i][j] = mfma16h(afr[i], bfr[0][j], acc[i][j]);
        __builtin_amdgcn_s_setprio(0);
        SCHED();
        if (st) { asm volatile("s_waitcnt vmcnt(2)" ::: "memory"); }
        else    { asm volatile("s_waitcnt vmcnt(0)" ::: "memory"); }
        SCHED(); SBAR(); SCHED();
#pragma unroll
        for (int f = 0; f < 4; f++) afr[f] = *(const f16x8*)&bp[aBase + 8192 + f * 512];
#pragma unroll
        for (int j = 0; j < 4; j++) bfr[1][j] = *(const f16x8*)&bp[bBase + 8192 + j * 512];
        if (st) STG2(nb, 2, Bw, n0, t + 1, 0)
        SBAR(); LGKM0(); SCHED();
        __builtin_amdgcn_s_setprio(1);
#pragma unroll
        for (int i = 0; i < 4; i++)
#pragma unroll
            for (int j = 0; j < 4; j++)
                acc[i][j] = mfma16h(afr[i], bfr[1][j], acc[i][j]);
        __builtin_amdgcn_s_setprio(0);
        SCHED(); SBAR(); SCHED();
#pragma unroll
        for (int f = 0; f < 4; f++) afr[f] = *(const f16x8*)&bp[aBase + 2048 + f * 512];
        if (st) STG2(nb, 1, Ax, m0, t + 1, 1)
        SBAR(); LGKM0(); SCHED();
        __builtin_amdgcn_s_setprio(1);
#pragma unroll
        for (int i = 0; i < 4; i++)
#pragma unroll
            for (int j = 0; j < 4; j++)
                acc[4 + i][j] = mfma16h(afr[i], bfr[0][j], acc[4 + i][j]);
        __builtin_amdgcn_s_setprio(0);
        SCHED(); SBAR(); SCHED();
#pragma unroll
        for (int f = 0; f < 4; f++) afr[f] = *(const f16x8*)&bp[aBase + 8192 + 2048 + f * 512];
        if (st) STG2(nb, 3, Bw, n0, t + 1, 1)
        SBAR(); LGKM0(); SCHED();
        __builtin_amdgcn_s_setprio(1);
#pragma unroll
        for (int i = 0; i < 4; i++)
#pragma unroll
            for (int j = 0; j < 4; j++)
                acc[4 + i][j] = mfma16h(afr[i], bfr[1][j], acc[4 + i][j]);
        __builtin_amdgcn_s_setprio(0);
        SCHED();
        if (st) { asm volatile("s_waitcnt vmcnt(4)" ::: "memory"); }
        SCHED(); SBAR(); SCHED();
    }

    float* ep = (float*)sm; // [32][264]
    for (int g = 0; g < 8; g++) {
        __syncthreads();
        if (wr == (g >> 2)) {
#pragma unroll
            for (int fi = 0; fi < 2; fi++) {
                int fm = (g & 3) * 2 + fi;
#pragma unroll
                for (int fn = 0; fn < 4; fn++)
#pragma unroll
                    for (int r = 0; r < 4; r++)
                        ep[(fi * 16 + (lane >> 4) * 4 + r) * 264 + wc * 64 + fn * 16 + lr] = acc[fm][fn][r];
            }
        }
        __syncthreads();
        int row = tid >> 4, c0 = (tid & 15) * 16;
        int grow = m0 + g * 32 + row;
        u16x8 h0, h1;
#pragma unroll
        for (int j = 0; j < 8; j++) {
            h0[j] = f2h(ep[row * 264 + c0 + j]);
            h1[j] = f2h(ep[row * 264 + c0 + 8 + j]);
        }
        if (sec < 2) {
            size_t o = (size_t)grow * 2048 + (n0 + c0);
            *(u16x8*)(QK + o) = h0; *(u16x8*)(QK + o + 8) = h1;
        } else {
            size_t o = (size_t)grow * 1024 + (n0 - 2048 + c0);
            *(u16x8*)(Vb + o) = h0; *(u16x8*)(Vb + o + 8) = h1;
        }
    }
}

// ---------------- final GEMM: attn @ Wo^T + bo -> f32 out (r7 2-phase, 2/CU, XCD swizzle) ----------------
// 1D grid of 256; work = (bid%8)*32 + bid/8: each XCD owns 8 contiguous m-rows.
__global__ __launch_bounds__(512, 2) void k_gemm_out(
    const u16* __restrict__ Ab, const u16* __restrict__ Bw,
    const float* __restrict__ bias, float* __restrict__ outp) {
    __shared__ __align__(16) u16 sm[32768];
    const int tid = threadIdx.x, wave = tid >> 6, lane = tid & 63;
    const int lr = lane & 15, lkq = lane >> 4;
    const int wr = wave >> 2, wc = wave & 3;
    const int bid = blockIdx.x;
    const int work = (bid & 7) * 32 + (bid >> 3);
    const int m0 = (work >> 2) * 256, n0 = (work & 3) * 256;

    int aoff[8], boff[4];
#pragma unroll
    for (int f = 0; f < 8; f++) {
        int row = wr * 128 + f * 16 + lr;
        aoff[f] = row * 32 + ((lkq ^ ((row >> 1) & 3)) * 8);
    }
#pragma unroll
    for (int f = 0; f < 4; f++) {
        int row = wc * 64 + f * 16 + lr;
        boff[f] = row * 32 + ((lkq ^ ((row >> 1) & 3)) * 8);
    }

    f32x4 acc[8][4];
#pragma unroll
    for (int i = 0; i < 8; i++)
#pragma unroll
        for (int j = 0; j < 4; j++)
#pragma unroll
            for (int r = 0; r < 4; r++) acc[i][j][r] = 0.f;

    STG(0, 0, Ab, m0, 0) STG(0, 1, Ab, m0, 0)
    STG(0, 2, Bw, n0, 0) STG(0, 3, Bw, n0, 0)
    asm volatile("s_waitcnt vmcnt(0)" ::: "memory");
    SCHED(); SBAR(); SCHED();

    int cb = 0;
    for (int t = 0; t < 32; ++t) {
        const u16* Abase = sm + cb * 16384;
        const u16* Bbase = Abase + 8192;
        f16x8 afr[4], bfr[4];
#pragma unroll
        for (int f = 0; f < 4; f++) bfr[f] = *(const f16x8*)&Bbase[boff[f]];
#pragma unroll
        for (int f = 0; f < 4; f++) afr[f] = *(const f16x8*)&Abase[aoff[f]];
        if (t < 31) {
            int kk = (t + 1) * 32;
            STG(cb ^ 1, 0, Ab, m0, kk) STG(cb ^ 1, 1, Ab, m0, kk)
            STG(cb ^ 1, 2, Bw, n0, kk) STG(cb ^ 1, 3, Bw, n0, kk)
        }
        SCHED(); SBAR(); LGKM0(); SCHED();
        __builtin_amdgcn_s_setprio(1);
#pragma unroll
        for (int i = 0; i < 4; i++)
#pragma unroll
            for (int j = 0; j < 4; j++)
                acc[i][j] = mfma16h(afr[i], bfr[j], acc[i][j]);
        __builtin_amdgcn_s_setprio(0);
        SCHED(); SBAR(); SCHED();
#pragma unroll
        for (int f = 0; f < 4; f++) afr[f] = *(const f16x8*)&Abase[aoff[4 + f]];
        SCHED(); SBAR(); LGKM0(); SCHED();
        __builtin_amdgcn_s_setprio(1);
#pragma unroll
        for (int i = 0; i < 4; i++)
#pragma unroll
            for (int j = 0; j < 4; j++)
                acc[4 + i][j] = mfma16h(afr[i], bfr[j], acc[4 + i][j]);
        __builtin_amdgcn_s_setprio(0);
        asm volatile("s_waitcnt vmcnt(0)" ::: "memory");
        SCHED(); SBAR(); SCHED();
        cb ^= 1;
    }

    float* ep = (float*)sm; // [32][264]
    for (int g = 0; g < 8; g++) {
        __syncthreads();
        if (wr == (g >> 2)) {
#pragma unroll
            for (int fi = 0; fi < 2; fi++) {
                int fm = (g & 3) * 2 + fi;
#pragma unroll
                for (int fn = 0; fn < 4; fn++)
#pragma unroll
                    for (int r = 0; r < 4; r++)
                        ep[(fi * 16 + (lane >> 4) * 4 + r) * 264 + wc * 64 + fn * 16 + lr] = acc[fm][fn][r];
            }
        }
        __syncthreads();
        int row = tid >> 4, c0 = (tid & 15) * 16;
        int grow = m0 + g * 32 + row;
        float vv[16];
#pragma unroll
        for (int j = 0; j < 16; j++) vv[j] = ep[row * 264 + c0 + j] + bias[n0 + c0 + j];
#pragma unroll
        for (int p = 0; p < 4; p++) {
            f32x4 tv;
#pragma unroll
            for (int q = 0; q < 4; q++) tv[q] = vv[p * 4 + q];
            *(f32x4*)(outp + (size_t)grow * 1024 + n0 + c0 + p * 4) = tv;
        }
    }
}

// ---------------- fused phi(K) + KV + Ksum: 8 slabs, reg prefetch, setprio ----------------
__global__ __launch_bounds__(256) void k_phik_kv(
    const u16* __restrict__ QK, const u16* __restrict__ wt,
    const u16* __restrict__ Vb, float* __restrict__ KVacc, float* __restrict__ Ksum) {
    __shared__ __align__(16) u16 sKh[64 * 72];
    __shared__ __align__(16) u16 sVt[64 * 72];
    __shared__ __align__(16) u16 sKfT[256 * 72];
    __shared__ float snsq[64];
    const int tid = threadIdx.x, wave = tid >> 6, lane = tid & 63;
    const int lr = lane & 15, lk = (lane >> 4) * 8;
    const int kc = blockIdx.x, bh = blockIdx.y;
    const int b = bh >> 4, h = bh & 15;

    f16x8 wb[4][2];
#pragma unroll
    for (int fn = 0; fn < 4; fn++)
#pragma unroll
        for (int ks = 0; ks < 2; ks++)
            wb[fn][ks] = *(const f16x8*)(wt + (size_t)(wave * 64 + fn * 16 + lr) * 64 + ks * 32 + lk);

    f32x4 akv[4][4];
#pragma unroll
    for (int i = 0; i < 4; i++)
#pragma unroll
        for (int j = 0; j < 4; j++)
#pragma unroll
            for (int r = 0; r < 4; r++) akv[i][j][r] = 0.f;
    float ksm[4] = {0.f, 0.f, 0.f, 0.f};

    // prefetch regs for iteration 0
    const int rowS = tid >> 2, cS = (tid & 3) * 16;
    size_t gK = ((size_t)(b * Ll + kc * 512 + rowS)) * 2048 + 1024 + h * 64 + cS;
    size_t gV = ((size_t)(b * Ll + kc * 512 + rowS)) * 1024 + h * 64 + cS;
    u16x8 kh0 = *(const u16x8*)(QK + gK);
    u16x8 kh1 = *(const u16x8*)(QK + gK + 8);
    u16x8 vv0 = *(const u16x8*)(Vb + gV);
    u16x8 vv1 = *(const u16x8*)(Vb + gV + 8);

    for (int it = 0; it < 8; it++) {
        __syncthreads();
        { // write K stage + nsq from regs
            *(u16x8*)&sKh[rowS * 72 + cS]     = kh0;
            *(u16x8*)&sKh[rowS * 72 + cS + 8] = kh1;
            float s = 0.f;
#pragma unroll
            for (int j = 0; j < 8; j++) {
                float a = h2f(kh0[j]); s += a * a;
                float c = h2f(kh1[j]); s += c * c;
            }
            s += __shfl_xor(s, 1); s += __shfl_xor(s, 2);
            if ((tid & 3) == 0) snsq[rowS] = s * 0.0625f;
        }
        { // write V transposed from regs
#pragma unroll
            for (int j = 0; j < 8; j++) {
                sVt[(cS + j) * 72 + rowS]     = vv0[j];
                sVt[(cS + 8 + j) * 72 + rowS] = vv1[j];
            }
        }
        __syncthreads();
        if (it < 7) { // issue next-iteration loads; land under MFMA phases
            gK += 131072; gV += 65536;
            kh0 = *(const u16x8*)(QK + gK);
            kh1 = *(const u16x8*)(QK + gK + 8);
            vv0 = *(const u16x8*)(Vb + gV);
            vv1 = *(const u16x8*)(Vb + gV + 8);
        }
#pragma unroll
        for (int fm = 0; fm < 4; fm++) {
            f32x4 ap[4];
#pragma unroll
            for (int fn = 0; fn < 4; fn++)
#pragma unroll
                for (int r = 0; r < 4; r++) ap[fn][r] = 0.f;
            __builtin_amdgcn_s_setprio(1);
#pragma unroll
            for (int ks = 0; ks < 2; ks++) {
                f16x8 aH = *(const f16x8*)&sKh[(fm * 16 + lr) * 72 + ks * 32 + lk];
#pragma unroll
                for (int fn = 0; fn < 4; fn++)
                    ap[fn] = mfma16h(aH, wb[fn][ks], ap[fn]);
            }
            __builtin_amdgcn_s_setprio(0);
#pragma unroll
            for (int fn = 0; fn < 4; fn++) {
                u16x4 pk;
#pragma unroll
                for (int r = 0; r < 4; r++) {
                    float ns = snsq[fm * 16 + (lane >> 4) * 4 + r];
                    float val = __expf(ap[fn][r] - ns) * 0.00390625f; // 1/256
                    ksm[fn] += val;
                    pk[r] = f2h(val);
                }
                *(u16x4*)&sKfT[(wave * 64 + fn * 16 + lr) * 72 + fm * 16 + (lane >> 4) * 4] = pk;
            }
        }
        __builtin_amdgcn_s_setprio(1);
#pragma unroll
        for (int ks = 0; ks < 2; ks++) {
            f16x8 a4[4], b4[4];
#pragma unroll
            for (int f = 0; f < 4; f++) {
                a4[f] = *(const f16x8*)&sKfT[(wave * 64 + f * 16 + lr) * 72 + ks * 32 + lk];
                b4[f] = *(const f16x8*)&sVt[(f * 16 + lr) * 72 + ks * 32 + lk];
            }
#pragma unroll
            for (int fm = 0; fm < 4; fm++)
#pragma unroll
                for (int fn = 0; fn < 4; fn++)
                    akv[fm][fn] = mfma16h(a4[fm], b4[fn], akv[fm][fn]);
        }
        __builtin_amdgcn_s_setprio(0);
    }
    // owned-slab stores (no atomics); 8 slabs
    const size_t base = ((size_t)(kc * 64 + bh)) << 14;
#pragma unroll
    for (int fm = 0; fm < 4; fm++)
#pragma unroll
        for (int fn = 0; fn < 4; fn++)
#pragma unroll
            for (int r = 0; r < 4; r++) {
                int m = wave * 64 + fm * 16 + (lane >> 4) * 4 + r;
                int d = fn * 16 + lr;
                KVacc[base + m * 64 + d] = akv[fm][fn][r];
            }
#pragma unroll
    for (int fn = 0; fn < 4; fn++) {
        ksm[fn] += __shfl_xor(ksm[fn], 16);
        ksm[fn] += __shfl_xor(ksm[fn], 32);
    }
    if (lane < 16) {
#pragma unroll
        for (int fn = 0; fn < 4; fn++)
            Ksum[(kc * 64 + bh) * 256 + wave * 64 + fn * 16 + lane] = ksm[fn];
    }
}

// ---------------- slab reduce: KVt[bh][d][m] = fp16(sum_kc KVacc), KsumR = sum_kc Ksum ----------------
__global__ __launch_bounds__(256) void k_kvt(const float* __restrict__ KVacc,
                                             const float* __restrict__ Ksum,
                                             u16* __restrict__ KVt, float* __restrict__ KsumR) {
    int i = blockIdx.x * 256 + threadIdx.x;
    if (blockIdx.x < 16384) {
        int bh = i >> 14, m = (i >> 6) & 255, d = i & 63;
        float s = 0.f;
#pragma unroll
        for (int kc = 0; kc < 8; kc++)
            s += KVacc[(((size_t)(kc * 64 + bh)) << 14) + m * 64 + d];
        KVt[((size_t)bh << 14) + d * 256 + m] = f2h(s);
    } else {
        int j = i - 4194304; // bh*256+m, 16384 total
        int bh = j >> 8, m = j & 255;
        float s = 0.f;
#pragma unroll
        for (int kc = 0; kc < 8; kc++)
            s += Ksum[(kc * 64 + bh) * 256 + m];
        KsumR[j] = s;
    }
}

// ---------------- fused phi(Q) + norm + attn: 4 subtiles/block, Q prefetch, setprio ----------------
__global__ __launch_bounds__(512) void k_phiq_attn(
    const u16* __restrict__ QK, const u16* __restrict__ wt,
    const u16* __restrict__ KVt, const float* __restrict__ Ksum,
    u16* __restrict__ attn) {
    __shared__ __align__(16) u16 sQh[64 * 72];
    __shared__ __align__(16) u16 sQf[64 * 264];
    __shared__ float sKs[256];
    __shared__ float snsq[64];
    __shared__ float snorm[64];
    const int tid = threadIdx.x, wave = tid >> 6, lane = tid & 63;
    const int lr = lane & 15, lk = (lane >> 4) * 8;
    const int bh = blockIdx.y, b = bh >> 4, h = bh & 15;
    const int mq = wave & 3;
    const int lh = wave >> 2;
    const int af = wave & 3;
    const int ad = wave >> 2;

    f16x8 wb[4][2];
#pragma unroll
    for (int fn = 0; fn < 4; fn++)
#pragma unroll
        for (int ks = 0; ks < 2; ks++)
            wb[fn][ks] = *(const f16x8*)(wt + (size_t)(mq * 64 + fn * 16 + lr) * 64 + ks * 32 + lk);
    f16x8 kvb[2][8];
#pragma unroll
    for (int fn = 0; fn < 2; fn++)
#pragma unroll
        for (int ks = 0; ks < 8; ks++)
            kvb[fn][ks] = *(const f16x8*)(KVt + ((size_t)bh << 14) +
                                          (size_t)(ad * 32 + fn * 16 + lr) * 256 + ks * 32 + lk);
    if (tid < 256) sKs[tid] = Ksum[bh * 256 + tid];

    // Q prefetch for st=0
    const int rowQ = tid >> 3, cQ = (tid & 7) * 8;
    size_t gQ = ((size_t)(b * Ll + blockIdx.x * 256 + rowQ)) * 2048 + h * 64 + cQ;
    u16x8 vh = *(const u16x8*)(QK + gQ);

    for (int st = 0; st < 4; st++) {
        const int l0 = blockIdx.x * 256 + st * 64;
        __syncthreads();
        { // stage Q + nsq from regs
            *(u16x8*)&sQh[rowQ * 72 + cQ] = vh;
            float s = 0.f;
#pragma unroll
            for (int j = 0; j < 8; j++) { float a = h2f(vh[j]); s += a * a; }
            s += __shfl_xor(s, 1); s += __shfl_xor(s, 2); s += __shfl_xor(s, 4);
            if ((tid & 7) == 0) snsq[rowQ] = s * 0.0625f;
        }
        __syncthreads();
#pragma unroll
        for (int fm = 0; fm < 2; fm++) {
            f32x4 ap[4];
#pragma unroll
            for (int fn = 0; fn < 4; fn++)
#pragma unroll
                for (int r = 0; r < 4; r++) ap[fn][r] = 0.f;
            __builtin_amdgcn_s_setprio(1);
#pragma unroll
            for (int ks = 0; ks < 2; ks++) {
                f16x8 aH = *(const f16x8*)&sQh[(lh * 32 + fm * 16 + lr) * 72 + ks * 32 + lk];
#pragma unroll
                for (int fn = 0; fn < 4; fn++)
                    ap[fn] = mfma16h(aH, wb[fn][ks], ap[fn]);
            }
            __builtin_amdgcn_s_setprio(0);
#pragma unroll
            for (int fn = 0; fn < 4; fn++)
#pragma unroll
                for (int r = 0; r < 4; r++) {
                    int l = lh * 32 + fm * 16 + (lane >> 4) * 4 + r;
                    int m = mq * 64 + fn * 16 + lr;
                    sQf[l * 264 + m] = f2h(__expf(ap[fn][r] - snsq[l]) * 0.0625f);
                }
        }
        if (st < 3) { // issue next Q load; lands under norm+attn+epilogue
            gQ += 131072;
            vh = *(const u16x8*)(QK + gQ);
        }
        __syncthreads();
        { // norm
            int l = tid >> 3, m0 = (tid & 7) * 32;
            float s = 0.f;
#pragma unroll
            for (int j4 = 0; j4 < 4; j4++) {
                u16x8 qv = *(const u16x8*)&sQf[l * 264 + m0 + j4 * 8];
#pragma unroll
                for (int j = 0; j < 8; j++) s += h2f(qv[j]) * sKs[m0 + j4 * 8 + j];
            }
            s += __shfl_xor(s, 1); s += __shfl_xor(s, 2); s += __shfl_xor(s, 4);
            if ((tid & 7) == 0) snorm[l] = s;
        }
        f32x4 aa[2];
#pragma unroll
        for (int fn = 0; fn < 2; fn++)
#pragma unroll
            for (int r = 0; r < 4; r++) aa[fn][r] = 0.f;
        __builtin_amdgcn_s_setprio(1);
#pragma unroll
        for (int ks = 0; ks < 8; ks++) {
            f16x8 a = *(const f16x8*)&sQf[(af * 16 + lr) * 264 + ks * 32 + lk];
            aa[0] = mfma16h(a, kvb[0][ks], aa[0]);
            aa[1] = mfma16h(a, kvb[1][ks], aa[1]);
        }
        __builtin_amdgcn_s_setprio(0);
        __syncthreads();
        float* ep = (float*)sQf; // [64][68]
#pragma unroll
        for (int fn = 0; fn < 2; fn++)
#pragma unroll
            for (int r = 0; r < 4; r++) {
                int l = af * 16 + (lane >> 4) * 4 + r;
                int d = ad * 32 + fn * 16 + lr;
                ep[l * 68 + d] = aa[fn][r];
            }
        __syncthreads();
        {
            int l = tid >> 3, d0 = (tid & 7) * 8;
            float inv = 1.0f / fmaxf(snorm[l], 6.25e-8f);
            u16x8 o;
#pragma unroll
            for (int j = 0; j < 8; j++) o[j] = f2h(ep[l * 68 + d0 + j] * inv);
            *(u16x8*)(attn + ((size_t)(b * Ll + l0 + l)) * 1024 + h * 64 + d0) = o;
        }
    }
}

extern "C" void kernel_launch(void* const* d_in, const int* in_sizes, int n_in,
                              void* d_out, int out_size, void* d_ws, size_t ws_size,
                              hipStream_t stream) {
    (void)in_sizes; (void)n_in; (void)out_size; (void)ws_size;
    const float* x  = (const float*)d_in[0];
    const float* Wq = (const float*)d_in[1];
    const float* Wk = (const float*)d_in[2];
    const float* Wv = (const float*)d_in[3];
    const float* Wo = (const float*)d_in[4];
    const float* bo = (const float*)d_in[5];
    const float* om = (const float*)d_in[6];

    char* w = (char*)d_ws;
    size_t o = 0;
    auto take = [&](size_t n) { char* p = w + o; o += n; return p; };
    u16* QK  = (u16*)take(67108864);   // [16384][2048] fp16: Q | K
    u16* Vb  = (u16*)take(33554432);   // [16384][1024] fp16
    u16* xh  = (u16*)take(33554432);   // x fp16
    u16* Wc  = (u16*)take(8388608);    // Wq|Wk|Wv|Wo fp16 [4096][1024]
    u16* wt  = (u16*)take(32768);      // omega^T scaled fp16 [256][64]
    float* KVacc = (float*)take(33554432); // 8 slabs x [64 bh][256 m][64 d]
    float* Ksum  = (float*)take(524288);   // 8 slabs x [64 bh][256 m]
    float* KsumR = (float*)take(65536);    // [64 bh][256 m]
    u16* KVt = (u16*)take(2097152);        // [64 bh][64 d][256 m]
    u16* Wof  = Wc + 3145728;
    u16* attn = Vb; // alias: V dead after k_phik_kv

    k_prep<<<20544, 256, 0, stream>>>(x, Wq, Wk, Wv, Wo, om, xh, Wc, wt);
    k_gemm_qkv<<<768, 512, 0, stream>>>(xh, Wc, QK, Vb);
    k_phik_kv<<<dim3(8, 64), 256, 0, stream>>>(QK, wt, Vb, KVacc, Ksum);
    k_kvt<<<16448, 256, 0, stream>>>(KVacc, Ksum, KVt, KsumR);
    k_phiq_attn<<<dim3(16, 64), 512, 0, stream>>>(QK, wt, KVt, KsumR, attn);
    k_gemm_out<<<256, 512, 0, stream>>>(attn, Wof, bo, (float*)d_out);
}

// Round 13
// 360.168 us; speedup vs baseline: 1.0474x; 1.0041x over previous
//
#include <hip/hip_runtime.h>

typedef unsigned short u16;
typedef __attribute__((ext_vector_type(4))) float f32x4;
typedef _Float16 f16x8 __attribute__((ext_vector_type(8)));
typedef __attribute__((ext_vector_type(4))) u16   u16x4;
typedef __attribute__((ext_vector_type(8))) u16   u16x8;

#define DEV static __device__ __forceinline__

constexpr int Ll = 4096;

DEV float h2f(u16 v) { _Float16 h; __builtin_memcpy(&h, &v, 2); return (float)h; }
DEV u16 f2h(float f) { _Float16 h = (_Float16)f; u16 u; __builtin_memcpy(&u, &h, 2); return u; }

DEV f32x4 mfma16h(f16x8 a, f16x8 b, f32x4 c) {
    return __builtin_amdgcn_mfma_f32_16x16x32_f16(a, b, c, 0, 0, 0);
}

#if defined(__has_builtin)
#if __has_builtin(__builtin_amdgcn_global_load_lds)
#define HAS_GLLDS 1
#endif
#endif
#ifndef HAS_GLLDS
#define HAS_GLLDS 0
#endif

#define SBAR()  __builtin_amdgcn_s_barrier()
#define SCHED() __builtin_amdgcn_sched_barrier(0)
#define LGKM0() asm volatile("s_waitcnt lgkmcnt(0)" ::: "memory")

// ---- m201-style stage: one region (256 rows x 32 cols fp16 = 16KB) = 2 gload units.
#if HAS_GLLDS
#define STG2(BUF, REG, SRC, ROWBASE, TK, KS)                                         \
  { _Pragma("unroll") for (int u_ = 0; u_ < 2; u_++) {                               \
      int row_ = u_ * 128 + wave * 16 + (lane >> 2);                                 \
      int c_ = lane & 3;                                                             \
      const u16* gp_ = (SRC) + (size_t)((ROWBASE) + row_) * 1024 + (TK) * 64         \
                        + (KS) * 32 + ((c_ ^ ((row_ >> 1) & 3)) * 8);                \
      __builtin_amdgcn_global_load_lds(                                              \
        (const __attribute__((address_space(1))) unsigned int*)gp_,                  \
        (__attribute__((address_space(3))) unsigned int*)(sm + (BUF) * 32768 +       \
          (REG) * 8192 + (u_ * 512 + wave * 64) * 8), 16, 0, 0); } }
#else
#define STG2(BUF, REG, SRC, ROWBASE, TK, KS)                                         \
  { _Pragma("unroll") for (int u_ = 0; u_ < 2; u_++) {                               \
      int row_ = u_ * 128 + wave * 16 + (lane >> 2);                                 \
      int c_ = lane & 3;                                                             \
      const u16* gp_ = (SRC) + (size_t)((ROWBASE) + row_) * 1024 + (TK) * 64         \
                        + (KS) * 32 + ((c_ ^ ((row_ >> 1) & 3)) * 8);                \
      *(u16x8*)(sm + (BUF) * 32768 + (REG) * 8192 + (u_ * 512 + wave * 64 + lane) * 8) \
          = *(const u16x8*)gp_; } }
#endif

// ---- 128x256 gemm_out staging: U=0 -> A rows 0..127 ; U=1,2 -> B rows (U-1)*128.. ----
// Buffer = 12288 halfs (24KB): A region [128][32] at 0, B region [256][32] at 4096.
#if HAS_GLLDS
#define STGO(BUF, U, SRC, ROWBASE, KK)                                               \
  { int rl_ = wave * 16 + (lane >> 2);                                               \
    int c_ = lane & 3;                                                               \
    int grow_ = (((U) >= 1) ? ((U) - 1) * 128 : 0) + rl_;                            \
    const u16* gp_ = (SRC) + (size_t)((ROWBASE) + grow_) * 1024 + (KK)               \
                     + ((c_ ^ ((rl_ >> 1) & 3)) * 8);                                \
    __builtin_amdgcn_global_load_lds(                                                \
        (const __attribute__((address_space(1))) unsigned int*)gp_,                  \
        (__attribute__((address_space(3))) unsigned int*)(sm + (BUF) * 12288 +       \
            (U) * 4096 + wave * 512), 16, 0, 0); }
#else
#define STGO(BUF, U, SRC, ROWBASE, KK)                                               \
  { int rl_ = wave * 16 + (lane >> 2);                                               \
    int c_ = lane & 3;                                                               \
    int grow_ = (((U) >= 1) ? ((U) - 1) * 128 : 0) + rl_;                            \
    const u16* gp_ = (SRC) + (size_t)((ROWBASE) + grow_) * 1024 + (KK)               \
                     + ((c_ ^ ((rl_ >> 1) & 3)) * 8);                                \
    *(u16x8*)(sm + (BUF) * 12288 + (U) * 4096 + wave * 512 + lane * 8)               \
        = *(const u16x8*)gp_; }
#endif

// ---------------- merged prep: x, Wq|Wk|Wv|Wo, omega ----------------
__global__ __launch_bounds__(256) void k_prep(
    const float* __restrict__ x, const float* __restrict__ Wq, const float* __restrict__ Wk,
    const float* __restrict__ Wv, const float* __restrict__ Wo, const float* __restrict__ om,
    u16* __restrict__ xh, u16* __restrict__ Wc, u16* __restrict__ wtp) {
    int bx = blockIdx.x, tid = threadIdx.x;
    if (bx < 16384) {
        size_t i = ((size_t)bx * 256 + tid) * 4;
        f32x4 v = *(const f32x4*)(x + i);
        u16x4 h;
#pragma unroll
        for (int j = 0; j < 4; j++) h[j] = f2h(v[j]);
        *(u16x4*)(xh + i) = h;
    } else if (bx < 20480) {
        int wsel = (bx - 16384) >> 10;
        const float* src = (wsel == 0) ? Wq : (wsel == 1) ? Wk : (wsel == 2) ? Wv : Wo;
        size_t i = ((size_t)((bx - 16384) & 1023) * 256 + tid) * 4;
        f32x4 v = *(const f32x4*)(src + i);
        u16x4 h;
#pragma unroll
        for (int j = 0; j < 4; j++) h[j] = f2h(v[j]);
        *(u16x4*)(Wc + (size_t)wsel * 1048576 + i) = h;
    } else {
        int i = (bx - 20480) * 256 + tid; // 16384
        int m = i >> 6, d = i & 63;
        wtp[i] = f2h(om[d * 256 + m] * 0.35355339059327373f);
    }
}

// ---------------- QKV GEMM: 256x256, BK=64, 8-phase, counted vmcnt, XCD swizzle (frozen) ----------------
__global__ __launch_bounds__(512, 1) void k_gemm_qkv(
    const u16* __restrict__ Ax, const u16* __restrict__ Bw,
    u16* __restrict__ QK, u16* __restrict__ Vb) {
    __shared__ __align__(16) u16 sm[65536]; // 128 KB
    const int tid = threadIdx.x, wave = tid >> 6, lane = tid & 63;
    const int lr = lane & 15, lkq = lane >> 4;
    const int wr = wave >> 2, wc = wave & 3;
    const int bid = blockIdx.x;
    const int work = (bid & 7) * 96 + (bid >> 3);
    const int m0 = (work / 12) * 256, n0 = (work % 12) * 256;
    const int sec = n0 >> 10;

    const int arow = wr * 128 + lr;
    const int aBase = arow * 32 + ((lkq ^ ((arow >> 1) & 3)) * 8);
    const int brow = wc * 64 + lr;
    const int bBase = 16384 + brow * 32 + ((lkq ^ ((brow >> 1) & 3)) * 8);

    f32x4 acc[8][4];
#pragma unroll
    for (int i = 0; i < 8; i++)
#pragma unroll
        for (int j = 0; j < 4; j++)
#pragma unroll
            for (int r = 0; r < 4; r++) acc[i][j][r] = 0.f;

    STG2(0, 0, Ax, m0, 0, 0)
    STG2(0, 2, Bw, n0, 0, 0)
    STG2(0, 1, Ax, m0, 0, 1)
    STG2(0, 3, Bw, n0, 0, 1)
    asm volatile("s_waitcnt vmcnt(4)" ::: "memory");
    SCHED(); SBAR(); SCHED();

    f16x8 bfr[2][4], afr[4];
    for (int t = 0; t < 16; ++t) {
        const u16* bp = sm + (t & 1) * 32768;
        const int nb = (t + 1) & 1;
        const bool st = t < 15;
#pragma unroll
        for (int f = 0; f < 4; f++) afr[f] = *(const f16x8*)&bp[aBase + f * 512];
#pragma unroll
        for (int j = 0; j < 4; j++) bfr[0][j] = *(const f16x8*)&bp[bBase + j * 512];
        if (st) STG2(nb, 0, Ax, m0, t + 1, 0)
        SBAR(); LGKM0(); SCHED();
        __builtin_amdgcn_s_setprio(1);
#pragma unroll
        for (int i = 0; i < 4; i++)
#pragma unroll
            for (int j = 0; j < 4; j++)
                acc[i][j] = mfma16h(afr[i], bfr[0][j], acc[i][j]);
        __builtin_amdgcn_s_setprio(0);
        SCHED();
        if (st) { asm volatile("s_waitcnt vmcnt(2)" ::: "memory"); }
        else    { asm volatile("s_waitcnt vmcnt(0)" ::: "memory"); }
        SCHED(); SBAR(); SCHED();
#pragma unroll
        for (int f = 0; f < 4; f++) afr[f] = *(const f16x8*)&bp[aBase + 8192 + f * 512];
#pragma unroll
        for (int j = 0; j < 4; j++) bfr[1][j] = *(const f16x8*)&bp[bBase + 8192 + j * 512];
        if (st) STG2(nb, 2, Bw, n0, t + 1, 0)
        SBAR(); LGKM0(); SCHED();
        __builtin_amdgcn_s_setprio(1);
#pragma unroll
        for (int i = 0; i < 4; i++)
#pragma unroll
            for (int j = 0; j < 4; j++)
                acc[i][j] = mfma16h(afr[i], bfr[1][j], acc[i][j]);
        __builtin_amdgcn_s_setprio(0);
        SCHED(); SBAR(); SCHED();
#pragma unroll
        for (int f = 0; f < 4; f++) afr[f] = *(const f16x8*)&bp[aBase + 2048 + f * 512];
        if (st) STG2(nb, 1, Ax, m0, t + 1, 1)
        SBAR(); LGKM0(); SCHED();
        __builtin_amdgcn_s_setprio(1);
#pragma unroll
        for (int i = 0; i < 4; i++)
#pragma unroll
            for (int j = 0; j < 4; j++)
                acc[4 + i][j] = mfma16h(afr[i], bfr[0][j], acc[4 + i][j]);
        __builtin_amdgcn_s_setprio(0);
        SCHED(); SBAR(); SCHED();
#pragma unroll
        for (int f = 0; f < 4; f++) afr[f] = *(const f16x8*)&bp[aBase + 8192 + 2048 + f * 512];
        if (st) STG2(nb, 3, Bw, n0, t + 1, 1)
        SBAR(); LGKM0(); SCHED();
        __builtin_amdgcn_s_setprio(1);
#pragma unroll
        for (int i = 0; i < 4; i++)
#pragma unroll
            for (int j = 0; j < 4; j++)
                acc[4 + i][j] = mfma16h(afr[i], bfr[1][j], acc[4 + i][j]);
        __builtin_amdgcn_s_setprio(0);
        SCHED();
        if (st) { asm volatile("s_waitcnt vmcnt(4)" ::: "memory"); }
        SCHED(); SBAR(); SCHED();
    }

    float* ep = (float*)sm; // [32][264]
    for (int g = 0; g < 8; g++) {
        __syncthreads();
        if (wr == (g >> 2)) {
#pragma unroll
            for (int fi = 0; fi < 2; fi++) {
                int fm = (g & 3) * 2 + fi;
#pragma unroll
                for (int fn = 0; fn < 4; fn++)
#pragma unroll
                    for (int r = 0; r < 4; r++)
                        ep[(fi * 16 + (lane >> 4) * 4 + r) * 264 + wc * 64 + fn * 16 + lr] = acc[fm][fn][r];
            }
        }
        __syncthreads();
        int row = tid >> 4, c0 = (tid & 15) * 16;
        int grow = m0 + g * 32 + row;
        u16x8 h0, h1;
#pragma unroll
        for (int j = 0; j < 8; j++) {
            h0[j] = f2h(ep[row * 264 + c0 + j]);
            h1[j] = f2h(ep[row * 264 + c0 + 8 + j]);
        }
        if (sec < 2) {
            size_t o = (size_t)grow * 2048 + (n0 + c0);
            *(u16x8*)(QK + o) = h0; *(u16x8*)(QK + o + 8) = h1;
        } else {
            size_t o = (size_t)grow * 1024 + (n0 - 2048 + c0);
            *(u16x8*)(Vb + o) = h0; *(u16x8*)(Vb + o + 8) = h1;
        }
    }
}

// ---------------- final GEMM: attn @ Wo^T + bo -> f32 out (128x256 tiles, 2 blocks/CU) ----------------
// 1D grid of 512; work = (bid%8)*64 + bid/8; m0 = (work>>2)*128, n0 = (work&3)*256.
__global__ __launch_bounds__(512, 2) void k_gemm_out(
    const u16* __restrict__ Ab, const u16* __restrict__ Bw,
    const float* __restrict__ bias, float* __restrict__ outp) {
    __shared__ __align__(16) u16 sm[24576]; // 48 KB: 2 bufs x (A[128][32] | B[256][32]); ep fits
    const int tid = threadIdx.x, wave = tid >> 6, lane = tid & 63;
    const int lr = lane & 15, lkq = lane >> 4;
    const int wr = wave >> 2, wc = wave & 3;
    const int bid = blockIdx.x;
    const int work = (bid & 7) * 64 + (bid >> 3);
    const int m0 = (work >> 2) * 128, n0 = (work & 3) * 256;

    int aoff[4], boff[4];
#pragma unroll
    for (int f = 0; f < 4; f++) {
        int row = wr * 64 + f * 16 + lr;
        aoff[f] = row * 32 + ((lkq ^ ((row >> 1) & 3)) * 8);
        int rowb = wc * 64 + f * 16 + lr;
        boff[f] = 4096 + rowb * 32 + ((lkq ^ ((rowb >> 1) & 3)) * 8);
    }

    f32x4 acc[4][4];
#pragma unroll
    for (int i = 0; i < 4; i++)
#pragma unroll
        for (int j = 0; j < 4; j++)
#pragma unroll
            for (int r = 0; r < 4; r++) acc[i][j][r] = 0.f;

    STGO(0, 0, Ab, m0, 0)
    STGO(0, 1, Bw, n0, 0)
    STGO(0, 2, Bw, n0, 0)
    asm volatile("s_waitcnt vmcnt(0)" ::: "memory");
    SCHED(); SBAR(); SCHED();

    int cb = 0;
    for (int t = 0; t < 32; ++t) {
        const u16* buf = sm + cb * 12288;
        f16x8 afr[4], bfr[4];
#pragma unroll
        for (int f = 0; f < 4; f++) {
            afr[f] = *(const f16x8*)&buf[aoff[f]];
            bfr[f] = *(const f16x8*)&buf[boff[f]];
        }
        if (t < 31) {
            int kk = (t + 1) * 32;
            STGO(cb ^ 1, 0, Ab, m0, kk)
            STGO(cb ^ 1, 1, Bw, n0, kk)
            STGO(cb ^ 1, 2, Bw, n0, kk)
        }
        SCHED(); SBAR(); LGKM0(); SCHED();
        __builtin_amdgcn_s_setprio(1);
#pragma unroll
        for (int i = 0; i < 4; i++)
#pragma unroll
            for (int j = 0; j < 4; j++)
                acc[i][j] = mfma16h(afr[i], bfr[j], acc[i][j]);
        __builtin_amdgcn_s_setprio(0);
        SCHED();
        if (t < 31) { asm volatile("s_waitcnt vmcnt(0)" ::: "memory"); }
        SCHED(); SBAR(); SCHED();
        cb ^= 1;
    }

    float* ep = (float*)sm; // [32][264] f32 = 33792 B (fits 48 KB)
    for (int g = 0; g < 4; g++) {
        __syncthreads();
        if (wr == (g >> 1)) {
#pragma unroll
            for (int fi = 0; fi < 2; fi++) {
                int fm = (g & 1) * 2 + fi;
#pragma unroll
                for (int fn = 0; fn < 4; fn++)
#pragma unroll
                    for (int r = 0; r < 4; r++)
                        ep[(fi * 16 + (lane >> 4) * 4 + r) * 264 + wc * 64 + fn * 16 + lr] = acc[fm][fn][r];
            }
        }
        __syncthreads();
        int row = tid >> 4, c0 = (tid & 15) * 16;
        int grow = m0 + g * 32 + row;
        float vv[16];
#pragma unroll
        for (int j = 0; j < 16; j++) vv[j] = ep[row * 264 + c0 + j] + bias[n0 + c0 + j];
#pragma unroll
        for (int p = 0; p < 4; p++) {
            f32x4 tv;
#pragma unroll
            for (int q = 0; q < 4; q++) tv[q] = vv[p * 4 + q];
            *(f32x4*)(outp + (size_t)grow * 1024 + n0 + c0 + p * 4) = tv;
        }
    }
}

// ---------------- fused phi(K) + KV + Ksum: 8 slabs, reg prefetch, setprio ----------------
__global__ __launch_bounds__(256) void k_phik_kv(
    const u16* __restrict__ QK, const u16* __restrict__ wt,
    const u16* __restrict__ Vb, float* __restrict__ KVacc, float* __restrict__ Ksum) {
    __shared__ __align__(16) u16 sKh[64 * 72];
    __shared__ __align__(16) u16 sVt[64 * 72];
    __shared__ __align__(16) u16 sKfT[256 * 72];
    __shared__ float snsq[64];
    const int tid = threadIdx.x, wave = tid >> 6, lane = tid & 63;
    const int lr = lane & 15, lk = (lane >> 4) * 8;
    const int kc = blockIdx.x, bh = blockIdx.y;
    const int b = bh >> 4, h = bh & 15;

    f16x8 wb[4][2];
#pragma unroll
    for (int fn = 0; fn < 4; fn++)
#pragma unroll
        for (int ks = 0; ks < 2; ks++)
            wb[fn][ks] = *(const f16x8*)(wt + (size_t)(wave * 64 + fn * 16 + lr) * 64 + ks * 32 + lk);

    f32x4 akv[4][4];
#pragma unroll
    for (int i = 0; i < 4; i++)
#pragma unroll
        for (int j = 0; j < 4; j++)
#pragma unroll
            for (int r = 0; r < 4; r++) akv[i][j][r] = 0.f;
    float ksm[4] = {0.f, 0.f, 0.f, 0.f};

    const int rowS = tid >> 2, cS = (tid & 3) * 16;
    size_t gK = ((size_t)(b * Ll + kc * 512 + rowS)) * 2048 + 1024 + h * 64 + cS;
    size_t gV = ((size_t)(b * Ll + kc * 512 + rowS)) * 1024 + h * 64 + cS;
    u16x8 kh0 = *(const u16x8*)(QK + gK);
    u16x8 kh1 = *(const u16x8*)(QK + gK + 8);
    u16x8 vv0 = *(const u16x8*)(Vb + gV);
    u16x8 vv1 = *(const u16x8*)(Vb + gV + 8);

    for (int it = 0; it < 8; it++) {
        __syncthreads();
        {
            *(u16x8*)&sKh[rowS * 72 + cS]     = kh0;
            *(u16x8*)&sKh[rowS * 72 + cS + 8] = kh1;
            float s = 0.f;
#pragma unroll
            for (int j = 0; j < 8; j++) {
                float a = h2f(kh0[j]); s += a * a;
                float c = h2f(kh1[j]); s += c * c;
            }
            s += __shfl_xor(s, 1); s += __shfl_xor(s, 2);
            if ((tid & 3) == 0) snsq[rowS] = s * 0.0625f;
        }
        {
#pragma unroll
            for (int j = 0; j < 8; j++) {
                sVt[(cS + j) * 72 + rowS]     = vv0[j];
                sVt[(cS + 8 + j) * 72 + rowS] = vv1[j];
            }
        }
        __syncthreads();
        if (it < 7) {
            gK += 131072; gV += 65536;
            kh0 = *(const u16x8*)(QK + gK);
            kh1 = *(const u16x8*)(QK + gK + 8);
            vv0 = *(const u16x8*)(Vb + gV);
            vv1 = *(const u16x8*)(Vb + gV + 8);
        }
#pragma unroll
        for (int fm = 0; fm < 4; fm++) {
            f32x4 ap[4];
#pragma unroll
            for (int fn = 0; fn < 4; fn++)
#pragma unroll
                for (int r = 0; r < 4; r++) ap[fn][r] = 0.f;
            __builtin_amdgcn_s_setprio(1);
#pragma unroll
            for (int ks = 0; ks < 2; ks++) {
                f16x8 aH = *(const f16x8*)&sKh[(fm * 16 + lr) * 72 + ks * 32 + lk];
#pragma unroll
                for (int fn = 0; fn < 4; fn++)
                    ap[fn] = mfma16h(aH, wb[fn][ks], ap[fn]);
            }
            __builtin_amdgcn_s_setprio(0);
#pragma unroll
            for (int fn = 0; fn < 4; fn++) {
                u16x4 pk;
#pragma unroll
                for (int r = 0; r < 4; r++) {
                    float ns = snsq[fm * 16 + (lane >> 4) * 4 + r];
                    float val = __expf(ap[fn][r] - ns) * 0.00390625f; // 1/256
                    ksm[fn] += val;
                    pk[r] = f2h(val);
                }
                *(u16x4*)&sKfT[(wave * 64 + fn * 16 + lr) * 72 + fm * 16 + (lane >> 4) * 4] = pk;
            }
        }
        __builtin_amdgcn_s_setprio(1);
#pragma unroll
        for (int ks = 0; ks < 2; ks++) {
            f16x8 a4[4], b4[4];
#pragma unroll
            for (int f = 0; f < 4; f++) {
                a4[f] = *(const f16x8*)&sKfT[(wave * 64 + f * 16 + lr) * 72 + ks * 32 + lk];
                b4[f] = *(const f16x8*)&sVt[(f * 16 + lr) * 72 + ks * 32 + lk];
            }
#pragma unroll
            for (int fm = 0; fm < 4; fm++)
#pragma unroll
                for (int fn = 0; fn < 4; fn++)
                    akv[fm][fn] = mfma16h(a4[fm], b4[fn], akv[fm][fn]);
        }
        __builtin_amdgcn_s_setprio(0);
    }
    const size_t base = ((size_t)(kc * 64 + bh)) << 14;
#pragma unroll
    for (int fm = 0; fm < 4; fm++)
#pragma unroll
        for (int fn = 0; fn < 4; fn++)
#pragma unroll
            for (int r = 0; r < 4; r++) {
                int m = wave * 64 + fm * 16 + (lane >> 4) * 4 + r;
                int d = fn * 16 + lr;
                KVacc[base + m * 64 + d] = akv[fm][fn][r];
            }
#pragma unroll
    for (int fn = 0; fn < 4; fn++) {
        ksm[fn] += __shfl_xor(ksm[fn], 16);
        ksm[fn] += __shfl_xor(ksm[fn], 32);
    }
    if (lane < 16) {
#pragma unroll
        for (int fn = 0; fn < 4; fn++)
            Ksum[(kc * 64 + bh) * 256 + wave * 64 + fn * 16 + lane] = ksm[fn];
    }
}

// ---------------- slab reduce: KVt[bh][d][m] = fp16(sum_kc KVacc), KsumR = sum_kc Ksum ----------------
__global__ __launch_bounds__(256) void k_kvt(const float* __restrict__ KVacc,
                                             const float* __restrict__ Ksum,
                                             u16* __restrict__ KVt, float* __restrict__ KsumR) {
    int i = blockIdx.x * 256 + threadIdx.x;
    if (blockIdx.x < 16384) {
        int bh = i >> 14, m = (i >> 6) & 255, d = i & 63;
        float s = 0.f;
#pragma unroll
        for (int kc = 0; kc < 8; kc++)
            s += KVacc[(((size_t)(kc * 64 + bh)) << 14) + m * 64 + d];
        KVt[((size_t)bh << 14) + d * 256 + m] = f2h(s);
    } else {
        int j = i - 4194304; // bh*256+m, 16384 total
        int bh = j >> 8, m = j & 255;
        float s = 0.f;
#pragma unroll
        for (int kc = 0; kc < 8; kc++)
            s += Ksum[(kc * 64 + bh) * 256 + m];
        KsumR[j] = s;
    }
}

// ---------------- fused phi(Q) + norm + attn: 4 subtiles/block, Q prefetch, setprio ----------------
__global__ __launch_bounds__(512) void k_phiq_attn(
    const u16* __restrict__ QK, const u16* __restrict__ wt,
    const u16* __restrict__ KVt, const float* __restrict__ Ksum,
    u16* __restrict__ attn) {
    __shared__ __align__(16) u16 sQh[64 * 72];
    __shared__ __align__(16) u16 sQf[64 * 264];
    __shared__ float sKs[256];
    __shared__ float snsq[64];
    __shared__ float snorm[64];
    const int tid = threadIdx.x, wave = tid >> 6, lane = tid & 63;
    const int lr = lane & 15, lk = (lane >> 4) * 8;
    const int bh = blockIdx.y, b = bh >> 4, h = bh & 15;
    const int mq = wave & 3;
    const int lh = wave >> 2;
    const int af = wave & 3;
    const int ad = wave >> 2;

    f16x8 wb[4][2];
#pragma unroll
    for (int fn = 0; fn < 4; fn++)
#pragma unroll
        for (int ks = 0; ks < 2; ks++)
            wb[fn][ks] = *(const f16x8*)(wt + (size_t)(mq * 64 + fn * 16 + lr) * 64 + ks * 32 + lk);
    f16x8 kvb[2][8];
#pragma unroll
    for (int fn = 0; fn < 2; fn++)
#pragma unroll
        for (int ks = 0; ks < 8; ks++)
            kvb[fn][ks] = *(const f16x8*)(KVt + ((size_t)bh << 14) +
                                          (size_t)(ad * 32 + fn * 16 + lr) * 256 + ks * 32 + lk);
    if (tid < 256) sKs[tid] = Ksum[bh * 256 + tid];

    const int rowQ = tid >> 3, cQ = (tid & 7) * 8;
    size_t gQ = ((size_t)(b * Ll + blockIdx.x * 256 + rowQ)) * 2048 + h * 64 + cQ;
    u16x8 vh = *(const u16x8*)(QK + gQ);

    for (int st = 0; st < 4; st++) {
        const int l0 = blockIdx.x * 256 + st * 64;
        __syncthreads();
        {
            *(u16x8*)&sQh[rowQ * 72 + cQ] = vh;
            float s = 0.f;
#pragma unroll
            for (int j = 0; j < 8; j++) { float a = h2f(vh[j]); s += a * a; }
            s += __shfl_xor(s, 1); s += __shfl_xor(s, 2); s += __shfl_xor(s, 4);
            if ((tid & 7) == 0) snsq[rowQ] = s * 0.0625f;
        }
        __syncthreads();
#pragma unroll
        for (int fm = 0; fm < 2; fm++) {
            f32x4 ap[4];
#pragma unroll
            for (int fn = 0; fn < 4; fn++)
#pragma unroll
                for (int r = 0; r < 4; r++) ap[fn][r] = 0.f;
            __builtin_amdgcn_s_setprio(1);
#pragma unroll
            for (int ks = 0; ks < 2; ks++) {
                f16x8 aH = *(const f16x8*)&sQh[(lh * 32 + fm * 16 + lr) * 72 + ks * 32 + lk];
#pragma unroll
                for (int fn = 0; fn < 4; fn++)
                    ap[fn] = mfma16h(aH, wb[fn][ks], ap[fn]);
            }
            __builtin_amdgcn_s_setprio(0);
#pragma unroll
            for (int fn = 0; fn < 4; fn++)
#pragma unroll
                for (int r = 0; r < 4; r++) {
                    int l = lh * 32 + fm * 16 + (lane >> 4) * 4 + r;
                    int m = mq * 64 + fn * 16 + lr;
                    sQf[l * 264 + m] = f2h(__expf(ap[fn][r] - snsq[l]) * 0.0625f);
                }
        }
        if (st < 3) {
            gQ += 131072;
            vh = *(const u16x8*)(QK + gQ);
        }
        __syncthreads();
        {
            int l = tid >> 3, m0 = (tid & 7) * 32;
            float s = 0.f;
#pragma unroll
            for (int j4 = 0; j4 < 4; j4++) {
                u16x8 qv = *(const u16x8*)&sQf[l * 264 + m0 + j4 * 8];
#pragma unroll
                for (int j = 0; j < 8; j++) s += h2f(qv[j]) * sKs[m0 + j4 * 8 + j];
            }
            s += __shfl_xor(s, 1); s += __shfl_xor(s, 2); s += __shfl_xor(s, 4);
            if ((tid & 7) == 0) snorm[l] = s;
        }
        f32x4 aa[2];
#pragma unroll
        for (int fn = 0; fn < 2; fn++)
#pragma unroll
            for (int r = 0; r < 4; r++) aa[fn][r] = 0.f;
        __builtin_amdgcn_s_setprio(1);
#pragma unroll
        for (int ks = 0; ks < 8; ks++) {
            f16x8 a = *(const f16x8*)&sQf[(af * 16 + lr) * 264 + ks * 32 + lk];
            aa[0] = mfma16h(a, kvb[0][ks], aa[0]);
            aa[1] = mfma16h(a, kvb[1][ks], aa[1]);
        }
        __builtin_amdgcn_s_setprio(0);
        __syncthreads();
        float* ep = (float*)sQf; // [64][68]
#pragma unroll
        for (int fn = 0; fn < 2; fn++)
#pragma unroll
            for (int r = 0; r < 4; r++) {
                int l = af * 16 + (lane >> 4) * 4 + r;
                int d = ad * 32 + fn * 16 + lr;
                ep[l * 68 + d] = aa[fn][r];
            }
        __syncthreads();
        {
            int l = tid >> 3, d0 = (tid & 7) * 8;
            float inv = 1.0f / fmaxf(snorm[l], 6.25e-8f);
            u16x8 o;
#pragma unroll
            for (int j = 0; j < 8; j++) o[j] = f2h(ep[l * 68 + d0 + j] * inv);
            *(u16x8*)(attn + ((size_t)(b * Ll + l0 + l)) * 1024 + h * 64 + d0) = o;
        }
    }
}

extern "C" void kernel_launch(void* const* d_in, const int* in_sizes, int n_in,
                              void* d_out, int out_size, void* d_ws, size_t ws_size,
                              hipStream_t stream) {
    (void)in_sizes; (void)n_in; (void)out_size; (void)ws_size;
    const float* x  = (const float*)d_in[0];
    const float* Wq = (const float*)d_in[1];
    const float* Wk = (const float*)d_in[2];
    const float* Wv = (const float*)d_in[3];
    const float* Wo = (const float*)d_in[4];
    const float* bo = (const float*)d_in[5];
    const float* om = (const float*)d_in[6];

    char* w = (char*)d_ws;
    size_t o = 0;
    auto take = [&](size_t n) { char* p = w + o; o += n; return p; };
    u16* QK  = (u16*)take(67108864);   // [16384][2048] fp16: Q | K
    u16* Vb  = (u16*)take(33554432);   // [16384][1024] fp16
    u16* xh  = (u16*)take(33554432);   // x fp16
    u16* Wc  = (u16*)take(8388608);    // Wq|Wk|Wv|Wo fp16 [4096][1024]
    u16* wt  = (u16*)take(32768);      // omega^T scaled fp16 [256][64]
    float* KVacc = (float*)take(33554432); // 8 slabs x [64 bh][256 m][64 d]
    float* Ksum  = (float*)take(524288);   // 8 slabs x [64 bh][256 m]
    float* KsumR = (float*)take(65536);    // [64 bh][256 m]
    u16* KVt = (u16*)take(2097152);        // [64 bh][64 d][256 m]
    u16* Wof  = Wc + 3145728;
    u16* attn = Vb; // alias: V dead after k_phik_kv

    k_prep<<<20544, 256, 0, stream>>>(x, Wq, Wk, Wv, Wo, om, xh, Wc, wt);
    k_gemm_qkv<<<768, 512, 0, stream>>>(xh, Wc, QK, Vb);
    k_phik_kv<<<dim3(8, 64), 256, 0, stream>>>(QK, wt, Vb, KVacc, Ksum);
    k_kvt<<<16448, 256, 0, stream>>>(KVacc, Ksum, KVt, KsumR);
    k_phiq_attn<<<dim3(16, 64), 512, 0, stream>>>(QK, wt, KVt, KsumR, attn);
    k_gemm_out<<<512, 512, 0, stream>>>(attn, Wof, bo, (float*)d_out);
}

// Round 14
// 358.636 us; speedup vs baseline: 1.0519x; 1.0043x over previous
//
#include <hip/hip_runtime.h>

typedef unsigned short u16;
typedef __attribute__((ext_vector_type(4))) float f32x4;
typedef _Float16 f16x8 __attribute__((ext_vector_type(8)));
typedef __attribute__((ext_vector_type(4))) u16   u16x4;
typedef __attribute__((ext_vector_type(8))) u16   u16x8;

#define DEV static __device__ __forceinline__

constexpr int Ll = 4096;

DEV float h2f(u16 v) { _Float16 h; __builtin_memcpy(&h, &v, 2); return (float)h; }
DEV u16 f2h(float f) { _Float16 h = (_Float16)f; u16 u; __builtin_memcpy(&u, &h, 2); return u; }

DEV f32x4 mfma16h(f16x8 a, f16x8 b, f32x4 c) {
    return __builtin_amdgcn_mfma_f32_16x16x32_f16(a, b, c, 0, 0, 0);
}

#if defined(__has_builtin)
#if __has_builtin(__builtin_amdgcn_global_load_lds)
#define HAS_GLLDS 1
#endif
#endif
#ifndef HAS_GLLDS
#define HAS_GLLDS 0
#endif

#define SBAR()  __builtin_amdgcn_s_barrier()
#define SCHED() __builtin_amdgcn_sched_barrier(0)
#define LGKM0() asm volatile("s_waitcnt lgkmcnt(0)" ::: "memory")

// ---- QKV staging: [256][64] tile (128B rows), st_16x32-style swizzle chunk^=(row&7).
// One unit J = 64 rows (8 rows/wave, 8 chunks of 16B per row). TB = tile base (halfs).
#if HAS_GLLDS
#define STG3(BUF, TB, J, SRC, ROWBASE, TK)                                           \
  { int row_ = (J) * 64 + wave * 8 + (lane >> 3);                                    \
    int cg_ = (lane & 7) ^ ((lane >> 3) & 7);                                        \
    const u16* gp_ = (SRC) + (size_t)((ROWBASE) + row_) * 1024 + (TK) * 64 + cg_ * 8;\
    __builtin_amdgcn_global_load_lds(                                                \
      (const __attribute__((address_space(1))) unsigned int*)gp_,                    \
      (__attribute__((address_space(3))) unsigned int*)(sm + (BUF) * 32768 +         \
        (TB) + (J) * 4096 + wave * 512), 16, 0, 0); }
#else
#define STG3(BUF, TB, J, SRC, ROWBASE, TK)                                           \
  { int row_ = (J) * 64 + wave * 8 + (lane >> 3);                                    \
    int cg_ = (lane & 7) ^ ((lane >> 3) & 7);                                        \
    const u16* gp_ = (SRC) + (size_t)((ROWBASE) + row_) * 1024 + (TK) * 64 + cg_ * 8;\
    *(u16x8*)(sm + (BUF) * 32768 + (TB) + (J) * 4096 + wave * 512 + lane * 8)        \
        = *(const u16x8*)gp_; }
#endif

// ---- 128x256 gemm_out staging: U=0 -> A rows 0..127 ; U=1,2 -> B rows (U-1)*128.. ----
// Buffer = 12288 halfs (24KB): A region [128][32] at 0, B region [256][32] at 4096.
#if HAS_GLLDS
#define STGO(BUF, U, SRC, ROWBASE, KK)                                               \
  { int rl_ = wave * 16 + (lane >> 2);                                               \
    int c_ = lane & 3;                                                               \
    int grow_ = (((U) >= 1) ? ((U) - 1) * 128 : 0) + rl_;                            \
    const u16* gp_ = (SRC) + (size_t)((ROWBASE) + grow_) * 1024 + (KK)               \
                     + ((c_ ^ ((rl_ >> 1) & 3)) * 8);                                \
    __builtin_amdgcn_global_load_lds(                                                \
        (const __attribute__((address_space(1))) unsigned int*)gp_,                  \
        (__attribute__((address_space(3))) unsigned int*)(sm + (BUF) * 12288 +       \
            (U) * 4096 + wave * 512), 16, 0, 0); }
#else
#define STGO(BUF, U, SRC, ROWBASE, KK)                                               \
  { int rl_ = wave * 16 + (lane >> 2);                                               \
    int c_ = lane & 3;                                                               \
    int grow_ = (((U) >= 1) ? ((U) - 1) * 128 : 0) + rl_;                            \
    const u16* gp_ = (SRC) + (size_t)((ROWBASE) + grow_) * 1024 + (KK)               \
                     + ((c_ ^ ((rl_ >> 1) & 3)) * 8);                                \
    *(u16x8*)(sm + (BUF) * 12288 + (U) * 4096 + wave * 512 + lane * 8)               \
        = *(const u16x8*)gp_; }
#endif

// ---------------- merged prep: x, Wq|Wk|Wv|Wo, omega ----------------
__global__ __launch_bounds__(256) void k_prep(
    const float* __restrict__ x, const float* __restrict__ Wq, const float* __restrict__ Wk,
    const float* __restrict__ Wv, const float* __restrict__ Wo, const float* __restrict__ om,
    u16* __restrict__ xh, u16* __restrict__ Wc, u16* __restrict__ wtp) {
    int bx = blockIdx.x, tid = threadIdx.x;
    if (bx < 16384) {
        size_t i = ((size_t)bx * 256 + tid) * 4;
        f32x4 v = *(const f32x4*)(x + i);
        u16x4 h;
#pragma unroll
        for (int j = 0; j < 4; j++) h[j] = f2h(v[j]);
        *(u16x4*)(xh + i) = h;
    } else if (bx < 20480) {
        int wsel = (bx - 16384) >> 10;
        const float* src = (wsel == 0) ? Wq : (wsel == 1) ? Wk : (wsel == 2) ? Wv : Wo;
        size_t i = ((size_t)((bx - 16384) & 1023) * 256 + tid) * 4;
        f32x4 v = *(const f32x4*)(src + i);
        u16x4 h;
#pragma unroll
        for (int j = 0; j < 4; j++) h[j] = f2h(v[j]);
        *(u16x4*)(Wc + (size_t)wsel * 1048576 + i) = h;
    } else {
        int i = (bx - 20480) * 256 + tid; // 16384
        int m = i >> 6, d = i & 63;
        wtp[i] = f2h(om[d * 256 + m] * 0.35355339059327373f);
    }
}

// ---------------- QKV GEMM: 256x256, BK=64, 4-phase, [256][64] swizzled LDS, XCD swizzle ----------------
// Burst-issue 8 stages in p0; single vmcnt(0) drain at end of p3 (~4 MFMA phases of cover).
__global__ __launch_bounds__(512, 1) void k_gemm_qkv(
    const u16* __restrict__ Ax, const u16* __restrict__ Bw,
    u16* __restrict__ QK, u16* __restrict__ Vb) {
    __shared__ __align__(16) u16 sm[65536]; // 128 KB: 2 bufs x (A[256][64] | B[256][64])
    const int tid = threadIdx.x, wave = tid >> 6, lane = tid & 63;
    const int lr = lane & 15, lkq = lane >> 4;
    const int wr = wave >> 2, wc = wave & 3;
    const int bid = blockIdx.x;
    const int work = (bid & 7) * 96 + (bid >> 3);
    const int m0 = (work / 12) * 256, n0 = (work % 12) * 256;
    const int sec = n0 >> 10;

    // frag base offsets: row*64 + ((ks*4+lkq)^(row&7))*8 ; row&7 == lr&7 for all frags
    const int e = lr & 7;
    const int aB0 = (wr * 128 + lr) * 64 + ((lkq ^ e) * 8);
    const int aB1 = aB0 ^ 32; // ks1: chunk' ^= 4  -> half-offset ^= 32
    const int bB0 = 16384 + (wc * 64 + lr) * 64 + ((lkq ^ e) * 8);
    const int bB1 = bB0 ^ 32;

    f32x4 acc[8][4];
#pragma unroll
    for (int i = 0; i < 8; i++)
#pragma unroll
        for (int j = 0; j < 4; j++)
#pragma unroll
            for (int r = 0; r < 4; r++) acc[i][j][r] = 0.f;

    // prologue: tile 0 (8 gloads), full drain
    STG3(0, 0,     0, Ax, m0, 0) STG3(0, 0,     1, Ax, m0, 0)
    STG3(0, 0,     2, Ax, m0, 0) STG3(0, 0,     3, Ax, m0, 0)
    STG3(0, 16384, 0, Bw, n0, 0) STG3(0, 16384, 1, Bw, n0, 0)
    STG3(0, 16384, 2, Bw, n0, 0) STG3(0, 16384, 3, Bw, n0, 0)
    asm volatile("s_waitcnt vmcnt(0)" ::: "memory");
    SCHED(); SBAR(); SCHED();

    f16x8 bfr[2][4], afr[4];
    for (int t = 0; t < 16; ++t) {
        const u16* bp = sm + (t & 1) * 32768;
        const int nb = (t + 1) & 1;
        const bool st = t < 15;
        // ---- p0: A ks0 fm0-3 + B ks0 reads; burst-issue all t+1 stages; 16 MFMA ----
#pragma unroll
        for (int f = 0; f < 4; f++) afr[f] = *(const f16x8*)&bp[aB0 + f * 1024];
#pragma unroll
        for (int j = 0; j < 4; j++) bfr[0][j] = *(const f16x8*)&bp[bB0 + j * 1024];
        if (st) {
            STG3(nb, 0,     0, Ax, m0, t + 1) STG3(nb, 0,     1, Ax, m0, t + 1)
            STG3(nb, 0,     2, Ax, m0, t + 1) STG3(nb, 0,     3, Ax, m0, t + 1)
            STG3(nb, 16384, 0, Bw, n0, t + 1) STG3(nb, 16384, 1, Bw, n0, t + 1)
            STG3(nb, 16384, 2, Bw, n0, t + 1) STG3(nb, 16384, 3, Bw, n0, t + 1)
        }
        SBAR(); LGKM0(); SCHED();
        __builtin_amdgcn_s_setprio(1);
#pragma unroll
        for (int i = 0; i < 4; i++)
#pragma unroll
            for (int j = 0; j < 4; j++)
                acc[i][j] = mfma16h(afr[i], bfr[0][j], acc[i][j]);
        __builtin_amdgcn_s_setprio(0);
        SCHED(); SBAR(); SCHED();
        // ---- p1: A ks1 fm0-3 + B ks1 reads; 16 MFMA ----
#pragma unroll
        for (int f = 0; f < 4; f++) afr[f] = *(const f16x8*)&bp[aB1 + f * 1024];
#pragma unroll
        for (int j = 0; j < 4; j++) bfr[1][j] = *(const f16x8*)&bp[bB1 + j * 1024];
        SBAR(); LGKM0(); SCHED();
        __builtin_amdgcn_s_setprio(1);
#pragma unroll
        for (int i = 0; i < 4; i++)
#pragma unroll
            for (int j = 0; j < 4; j++)
                acc[i][j] = mfma16h(afr[i], bfr[1][j], acc[i][j]);
        __builtin_amdgcn_s_setprio(0);
        SCHED(); SBAR(); SCHED();
        // ---- p2: A ks0 fm4-7 reads (B ks0 in regs); 16 MFMA ----
#pragma unroll
        for (int f = 0; f < 4; f++) afr[f] = *(const f16x8*)&bp[aB0 + 4096 + f * 1024];
        SBAR(); LGKM0(); SCHED();
        __builtin_amdgcn_s_setprio(1);
#pragma unroll
        for (int i = 0; i < 4; i++)
#pragma unroll
            for (int j = 0; j < 4; j++)
                acc[4 + i][j] = mfma16h(afr[i], bfr[0][j], acc[4 + i][j]);
        __builtin_amdgcn_s_setprio(0);
        SCHED(); SBAR(); SCHED();
        // ---- p3: A ks1 fm4-7 reads; 16 MFMA; drain stages ----
#pragma unroll
        for (int f = 0; f < 4; f++) afr[f] = *(const f16x8*)&bp[aB1 + 4096 + f * 1024];
        SBAR(); LGKM0(); SCHED();
        __builtin_amdgcn_s_setprio(1);
#pragma unroll
        for (int i = 0; i < 4; i++)
#pragma unroll
            for (int j = 0; j < 4; j++)
                acc[4 + i][j] = mfma16h(afr[i], bfr[1][j], acc[4 + i][j]);
        __builtin_amdgcn_s_setprio(0);
        SCHED();
        if (st) { asm volatile("s_waitcnt vmcnt(0)" ::: "memory"); }
        SCHED(); SBAR(); SCHED();
    }

    float* ep = (float*)sm; // [32][264]
    for (int g = 0; g < 8; g++) {
        __syncthreads();
        if (wr == (g >> 2)) {
#pragma unroll
            for (int fi = 0; fi < 2; fi++) {
                int fm = (g & 3) * 2 + fi;
#pragma unroll
                for (int fn = 0; fn < 4; fn++)
#pragma unroll
                    for (int r = 0; r < 4; r++)
                        ep[(fi * 16 + (lane >> 4) * 4 + r) * 264 + wc * 64 + fn * 16 + lr] = acc[fm][fn][r];
            }
        }
        __syncthreads();
        int row = tid >> 4, c0 = (tid & 15) * 16;
        int grow = m0 + g * 32 + row;
        u16x8 h0, h1;
#pragma unroll
        for (int j = 0; j < 8; j++) {
            h0[j] = f2h(ep[row * 264 + c0 + j]);
            h1[j] = f2h(ep[row * 264 + c0 + 8 + j]);
        }
        if (sec < 2) {
            size_t o = (size_t)grow * 2048 + (n0 + c0);
            *(u16x8*)(QK + o) = h0; *(u16x8*)(QK + o + 8) = h1;
        } else {
            size_t o = (size_t)grow * 1024 + (n0 - 2048 + c0);
            *(u16x8*)(Vb + o) = h0; *(u16x8*)(Vb + o + 8) = h1;
        }
    }
}

// ---------------- final GEMM: attn @ Wo^T + bo -> f32 out (128x256 tiles, 2 blocks/CU) ----------------
__global__ __launch_bounds__(512, 2) void k_gemm_out(
    const u16* __restrict__ Ab, const u16* __restrict__ Bw,
    const float* __restrict__ bias, float* __restrict__ outp) {
    __shared__ __align__(16) u16 sm[24576]; // 48 KB
    const int tid = threadIdx.x, wave = tid >> 6, lane = tid & 63;
    const int lr = lane & 15, lkq = lane >> 4;
    const int wr = wave >> 2, wc = wave & 3;
    const int bid = blockIdx.x;
    const int work = (bid & 7) * 64 + (bid >> 3);
    const int m0 = (work >> 2) * 128, n0 = (work & 3) * 256;

    int aoff[4], boff[4];
#pragma unroll
    for (int f = 0; f < 4; f++) {
        int row = wr * 64 + f * 16 + lr;
        aoff[f] = row * 32 + ((lkq ^ ((row >> 1) & 3)) * 8);
        int rowb = wc * 64 + f * 16 + lr;
        boff[f] = 4096 + rowb * 32 + ((lkq ^ ((rowb >> 1) & 3)) * 8);
    }

    f32x4 acc[4][4];
#pragma unroll
    for (int i = 0; i < 4; i++)
#pragma unroll
        for (int j = 0; j < 4; j++)
#pragma unroll
            for (int r = 0; r < 4; r++) acc[i][j][r] = 0.f;

    STGO(0, 0, Ab, m0, 0)
    STGO(0, 1, Bw, n0, 0)
    STGO(0, 2, Bw, n0, 0)
    asm volatile("s_waitcnt vmcnt(0)" ::: "memory");
    SCHED(); SBAR(); SCHED();

    int cb = 0;
    for (int t = 0; t < 32; ++t) {
        const u16* buf = sm + cb * 12288;
        f16x8 afr[4], bfr[4];
#pragma unroll
        for (int f = 0; f < 4; f++) {
            afr[f] = *(const f16x8*)&buf[aoff[f]];
            bfr[f] = *(const f16x8*)&buf[boff[f]];
        }
        if (t < 31) {
            int kk = (t + 1) * 32;
            STGO(cb ^ 1, 0, Ab, m0, kk)
            STGO(cb ^ 1, 1, Bw, n0, kk)
            STGO(cb ^ 1, 2, Bw, n0, kk)
        }
        SCHED(); SBAR(); LGKM0(); SCHED();
        __builtin_amdgcn_s_setprio(1);
#pragma unroll
        for (int i = 0; i < 4; i++)
#pragma unroll
            for (int j = 0; j < 4; j++)
                acc[i][j] = mfma16h(afr[i], bfr[j], acc[i][j]);
        __builtin_amdgcn_s_setprio(0);
        SCHED();
        if (t < 31) { asm volatile("s_waitcnt vmcnt(0)" ::: "memory"); }
        SCHED(); SBAR(); SCHED();
        cb ^= 1;
    }

    float* ep = (float*)sm; // [32][264] f32
    for (int g = 0; g < 4; g++) {
        __syncthreads();
        if (wr == (g >> 1)) {
#pragma unroll
            for (int fi = 0; fi < 2; fi++) {
                int fm = (g & 1) * 2 + fi;
#pragma unroll
                for (int fn = 0; fn < 4; fn++)
#pragma unroll
                    for (int r = 0; r < 4; r++)
                        ep[(fi * 16 + (lane >> 4) * 4 + r) * 264 + wc * 64 + fn * 16 + lr] = acc[fm][fn][r];
            }
        }
        __syncthreads();
        int row = tid >> 4, c0 = (tid & 15) * 16;
        int grow = m0 + g * 32 + row;
        float vv[16];
#pragma unroll
        for (int j = 0; j < 16; j++) vv[j] = ep[row * 264 + c0 + j] + bias[n0 + c0 + j];
#pragma unroll
        for (int p = 0; p < 4; p++) {
            f32x4 tv;
#pragma unroll
            for (int q = 0; q < 4; q++) tv[q] = vv[p * 4 + q];
            *(f32x4*)(outp + (size_t)grow * 1024 + n0 + c0 + p * 4) = tv;
        }
    }
}

// ---------------- fused phi(K) + KV + Ksum: 8 slabs, reg prefetch, setprio ----------------
__global__ __launch_bounds__(256) void k_phik_kv(
    const u16* __restrict__ QK, const u16* __restrict__ wt,
    const u16* __restrict__ Vb, float* __restrict__ KVacc, float* __restrict__ Ksum) {
    __shared__ __align__(16) u16 sKh[64 * 72];
    __shared__ __align__(16) u16 sVt[64 * 72];
    __shared__ __align__(16) u16 sKfT[256 * 72];
    __shared__ float snsq[64];
    const int tid = threadIdx.x, wave = tid >> 6, lane = tid & 63;
    const int lr = lane & 15, lk = (lane >> 4) * 8;
    const int kc = blockIdx.x, bh = blockIdx.y;
    const int b = bh >> 4, h = bh & 15;

    f16x8 wb[4][2];
#pragma unroll
    for (int fn = 0; fn < 4; fn++)
#pragma unroll
        for (int ks = 0; ks < 2; ks++)
            wb[fn][ks] = *(const f16x8*)(wt + (size_t)(wave * 64 + fn * 16 + lr) * 64 + ks * 32 + lk);

    f32x4 akv[4][4];
#pragma unroll
    for (int i = 0; i < 4; i++)
#pragma unroll
        for (int j = 0; j < 4; j++)
#pragma unroll
            for (int r = 0; r < 4; r++) akv[i][j][r] = 0.f;
    float ksm[4] = {0.f, 0.f, 0.f, 0.f};

    const int rowS = tid >> 2, cS = (tid & 3) * 16;
    size_t gK = ((size_t)(b * Ll + kc * 512 + rowS)) * 2048 + 1024 + h * 64 + cS;
    size_t gV = ((size_t)(b * Ll + kc * 512 + rowS)) * 1024 + h * 64 + cS;
    u16x8 kh0 = *(const u16x8*)(QK + gK);
    u16x8 kh1 = *(const u16x8*)(QK + gK + 8);
    u16x8 vv0 = *(const u16x8*)(Vb + gV);
    u16x8 vv1 = *(const u16x8*)(Vb + gV + 8);

    for (int it = 0; it < 8; it++) {
        __syncthreads();
        {
            *(u16x8*)&sKh[rowS * 72 + cS]     = kh0;
            *(u16x8*)&sKh[rowS * 72 + cS + 8] = kh1;
            float s = 0.f;
#pragma unroll
            for (int j = 0; j < 8; j++) {
                float a = h2f(kh0[j]); s += a * a;
                float c = h2f(kh1[j]); s += c * c;
            }
            s += __shfl_xor(s, 1); s += __shfl_xor(s, 2);
            if ((tid & 3) == 0) snsq[rowS] = s * 0.0625f;
        }
        {
#pragma unroll
            for (int j = 0; j < 8; j++) {
                sVt[(cS + j) * 72 + rowS]     = vv0[j];
                sVt[(cS + 8 + j) * 72 + rowS] = vv1[j];
            }
        }
        __syncthreads();
        if (it < 7) {
            gK += 131072; gV += 65536;
            kh0 = *(const u16x8*)(QK + gK);
            kh1 = *(const u16x8*)(QK + gK + 8);
            vv0 = *(const u16x8*)(Vb + gV);
            vv1 = *(const u16x8*)(Vb + gV + 8);
        }
#pragma unroll
        for (int fm = 0; fm < 4; fm++) {
            f32x4 ap[4];
#pragma unroll
            for (int fn = 0; fn < 4; fn++)
#pragma unroll
                for (int r = 0; r < 4; r++) ap[fn][r] = 0.f;
            __builtin_amdgcn_s_setprio(1);
#pragma unroll
            for (int ks = 0; ks < 2; ks++) {
                f16x8 aH = *(const f16x8*)&sKh[(fm * 16 + lr) * 72 + ks * 32 + lk];
#pragma unroll
                for (int fn = 0; fn < 4; fn++)
                    ap[fn] = mfma16h(aH, wb[fn][ks], ap[fn]);
            }
            __builtin_amdgcn_s_setprio(0);
#pragma unroll
            for (int fn = 0; fn < 4; fn++) {
                u16x4 pk;
#pragma unroll
                for (int r = 0; r < 4; r++) {
                    float ns = snsq[fm * 16 + (lane >> 4) * 4 + r];
                    float val = __expf(ap[fn][r] - ns) * 0.00390625f; // 1/256
                    ksm[fn] += val;
                    pk[r] = f2h(val);
                }
                *(u16x4*)&sKfT[(wave * 64 + fn * 16 + lr) * 72 + fm * 16 + (lane >> 4) * 4] = pk;
            }
        }
        __builtin_amdgcn_s_setprio(1);
#pragma unroll
        for (int ks = 0; ks < 2; ks++) {
            f16x8 a4[4], b4[4];
#pragma unroll
            for (int f = 0; f < 4; f++) {
                a4[f] = *(const f16x8*)&sKfT[(wave * 64 + f * 16 + lr) * 72 + ks * 32 + lk];
                b4[f] = *(const f16x8*)&sVt[(f * 16 + lr) * 72 + ks * 32 + lk];
            }
#pragma unroll
            for (int fm = 0; fm < 4; fm++)
#pragma unroll
                for (int fn = 0; fn < 4; fn++)
                    akv[fm][fn] = mfma16h(a4[fm], b4[fn], akv[fm][fn]);
        }
        __builtin_amdgcn_s_setprio(0);
    }
    const size_t base = ((size_t)(kc * 64 + bh)) << 14;
#pragma unroll
    for (int fm = 0; fm < 4; fm++)
#pragma unroll
        for (int fn = 0; fn < 4; fn++)
#pragma unroll
            for (int r = 0; r < 4; r++) {
                int m = wave * 64 + fm * 16 + (lane >> 4) * 4 + r;
                int d = fn * 16 + lr;
                KVacc[base + m * 64 + d] = akv[fm][fn][r];
            }
#pragma unroll
    for (int fn = 0; fn < 4; fn++) {
        ksm[fn] += __shfl_xor(ksm[fn], 16);
        ksm[fn] += __shfl_xor(ksm[fn], 32);
    }
    if (lane < 16) {
#pragma unroll
        for (int fn = 0; fn < 4; fn++)
            Ksum[(kc * 64 + bh) * 256 + wave * 64 + fn * 16 + lane] = ksm[fn];
    }
}

// ---------------- slab reduce: KVt[bh][d][m] = fp16(sum_kc KVacc), KsumR = sum_kc Ksum ----------------
__global__ __launch_bounds__(256) void k_kvt(const float* __restrict__ KVacc,
                                             const float* __restrict__ Ksum,
                                             u16* __restrict__ KVt, float* __restrict__ KsumR) {
    int i = blockIdx.x * 256 + threadIdx.x;
    if (blockIdx.x < 16384) {
        int bh = i >> 14, m = (i >> 6) & 255, d = i & 63;
        float s = 0.f;
#pragma unroll
        for (int kc = 0; kc < 8; kc++)
            s += KVacc[(((size_t)(kc * 64 + bh)) << 14) + m * 64 + d];
        KVt[((size_t)bh << 14) + d * 256 + m] = f2h(s);
    } else {
        int j = i - 4194304; // bh*256+m, 16384 total
        int bh = j >> 8, m = j & 255;
        float s = 0.f;
#pragma unroll
        for (int kc = 0; kc < 8; kc++)
            s += Ksum[(kc * 64 + bh) * 256 + m];
        KsumR[j] = s;
    }
}

// ---------------- fused phi(Q) + norm + attn: 4 subtiles/block, Q prefetch, setprio ----------------
__global__ __launch_bounds__(512) void k_phiq_attn(
    const u16* __restrict__ QK, const u16* __restrict__ wt,
    const u16* __restrict__ KVt, const float* __restrict__ Ksum,
    u16* __restrict__ attn) {
    __shared__ __align__(16) u16 sQh[64 * 72];
    __shared__ __align__(16) u16 sQf[64 * 264];
    __shared__ float sKs[256];
    __shared__ float snsq[64];
    __shared__ float snorm[64];
    const int tid = threadIdx.x, wave = tid >> 6, lane = tid & 63;
    const int lr = lane & 15, lk = (lane >> 4) * 8;
    const int bh = blockIdx.y, b = bh >> 4, h = bh & 15;
    const int mq = wave & 3;
    const int lh = wave >> 2;
    const int af = wave & 3;
    const int ad = wave >> 2;

    f16x8 wb[4][2];
#pragma unroll
    for (int fn = 0; fn < 4; fn++)
#pragma unroll
        for (int ks = 0; ks < 2; ks++)
            wb[fn][ks] = *(const f16x8*)(wt + (size_t)(mq * 64 + fn * 16 + lr) * 64 + ks * 32 + lk);
    f16x8 kvb[2][8];
#pragma unroll
    for (int fn = 0; fn < 2; fn++)
#pragma unroll
        for (int ks = 0; ks < 8; ks++)
            kvb[fn][ks] = *(const f16x8*)(KVt + ((size_t)bh << 14) +
                                          (size_t)(ad * 32 + fn * 16 + lr) * 256 + ks * 32 + lk);
    if (tid < 256) sKs[tid] = Ksum[bh * 256 + tid];

    const int rowQ = tid >> 3, cQ = (tid & 7) * 8;
    size_t gQ = ((size_t)(b * Ll + blockIdx.x * 256 + rowQ)) * 2048 + h * 64 + cQ;
    u16x8 vh = *(const u16x8*)(QK + gQ);

    for (int st = 0; st < 4; st++) {
        const int l0 = blockIdx.x * 256 + st * 64;
        __syncthreads();
        {
            *(u16x8*)&sQh[rowQ * 72 + cQ] = vh;
            float s = 0.f;
#pragma unroll
            for (int j = 0; j < 8; j++) { float a = h2f(vh[j]); s += a * a; }
            s += __shfl_xor(s, 1); s += __shfl_xor(s, 2); s += __shfl_xor(s, 4);
            if ((tid & 7) == 0) snsq[rowQ] = s * 0.0625f;
        }
        __syncthreads();
#pragma unroll
        for (int fm = 0; fm < 2; fm++) {
            f32x4 ap[4];
#pragma unroll
            for (int fn = 0; fn < 4; fn++)
#pragma unroll
                for (int r = 0; r < 4; r++) ap[fn][r] = 0.f;
            __builtin_amdgcn_s_setprio(1);
#pragma unroll
            for (int ks = 0; ks < 2; ks++) {
                f16x8 aH = *(const f16x8*)&sQh[(lh * 32 + fm * 16 + lr) * 72 + ks * 32 + lk];
#pragma unroll
                for (int fn = 0; fn < 4; fn++)
                    ap[fn] = mfma16h(aH, wb[fn][ks], ap[fn]);
            }
            __builtin_amdgcn_s_setprio(0);
#pragma unroll
            for (int fn = 0; fn < 4; fn++)
#pragma unroll
                for (int r = 0; r < 4; r++) {
                    int l = lh * 32 + fm * 16 + (lane >> 4) * 4 + r;
                    int m = mq * 64 + fn * 16 + lr;
                    sQf[l * 264 + m] = f2h(__expf(ap[fn][r] - snsq[l]) * 0.0625f);
                }
        }
        if (st < 3) {
            gQ += 131072;
            vh = *(const u16x8*)(QK + gQ);
        }
        __syncthreads();
        {
            int l = tid >> 3, m0 = (tid & 7) * 32;
            float s = 0.f;
#pragma unroll
            for (int j4 = 0; j4 < 4; j4++) {
                u16x8 qv = *(const u16x8*)&sQf[l * 264 + m0 + j4 * 8];
#pragma unroll
                for (int j = 0; j < 8; j++) s += h2f(qv[j]) * sKs[m0 + j4 * 8 + j];
            }
            s += __shfl_xor(s, 1); s += __shfl_xor(s, 2); s += __shfl_xor(s, 4);
            if ((tid & 7) == 0) snorm[l] = s;
        }
        f32x4 aa[2];
#pragma unroll
        for (int fn = 0; fn < 2; fn++)
#pragma unroll
            for (int r = 0; r < 4; r++) aa[fn][r] = 0.f;
        __builtin_amdgcn_s_setprio(1);
#pragma unroll
        for (int ks = 0; ks < 8; ks++) {
            f16x8 a = *(const f16x8*)&sQf[(af * 16 + lr) * 264 + ks * 32 + lk];
            aa[0] = mfma16h(a, kvb[0][ks], aa[0]);
            aa[1] = mfma16h(a, kvb[1][ks], aa[1]);
        }
        __builtin_amdgcn_s_setprio(0);
        __syncthreads();
        float* ep = (float*)sQf; // [64][68]
#pragma unroll
        for (int fn = 0; fn < 2; fn++)
#pragma unroll
            for (int r = 0; r < 4; r++) {
                int l = af * 16 + (lane >> 4) * 4 + r;
                int d = ad * 32 + fn * 16 + lr;
                ep[l * 68 + d] = aa[fn][r];
            }
        __syncthreads();
        {
            int l = tid >> 3, d0 = (tid & 7) * 8;
            float inv = 1.0f / fmaxf(snorm[l], 6.25e-8f);
            u16x8 o;
#pragma unroll
            for (int j = 0; j < 8; j++) o[j] = f2h(ep[l * 68 + d0 + j] * inv);
            *(u16x8*)(attn + ((size_t)(b * Ll + l0 + l)) * 1024 + h * 64 + d0) = o;
        }
    }
}

extern "C" void kernel_launch(void* const* d_in, const int* in_sizes, int n_in,
                              void* d_out, int out_size, void* d_ws, size_t ws_size,
                              hipStream_t stream) {
    (void)in_sizes; (void)n_in; (void)out_size; (void)ws_size;
    const float* x  = (const float*)d_in[0];
    const float* Wq = (const float*)d_in[1];
    const float* Wk = (const float*)d_in[2];
    const float* Wv = (const float*)d_in[3];
    const float* Wo = (const float*)d_in[4];
    const float* bo = (const float*)d_in[5];
    const float* om = (const float*)d_in[6];

    char* w = (char*)d_ws;
    size_t o = 0;
    auto take = [&](size_t n) { char* p = w + o; o += n; return p; };
    u16* QK  = (u16*)take(67108864);   // [16384][2048] fp16: Q | K
    u16* Vb  = (u16*)take(33554432);   // [16384][1024] fp16
    u16* xh  = (u16*)take(33554432);   // x fp16
    u16* Wc  = (u16*)take(8388608);    // Wq|Wk|Wv|Wo fp16 [4096][1024]
    u16* wt  = (u16*)take(32768);      // omega^T scaled fp16 [256][64]
    float* KVacc = (float*)take(33554432); // 8 slabs x [64 bh][256 m][64 d]
    float* Ksum  = (float*)take(524288);   // 8 slabs x [64 bh][256 m]
    float* KsumR = (float*)take(65536);    // [64 bh][256 m]
    u16* KVt = (u16*)take(2097152);        // [64 bh][64 d][256 m]
    u16* Wof  = Wc + 3145728;
    u16* attn = Vb; // alias: V dead after k_phik_kv

    k_prep<<<20544, 256, 0, stream>>>(x, Wq, Wk, Wv, Wo, om, xh, Wc, wt);
    k_gemm_qkv<<<768, 512, 0, stream>>>(xh, Wc, QK, Vb);
    k_phik_kv<<<dim3(8, 64), 256, 0, stream>>>(QK, wt, Vb, KVacc, Ksum);
    k_kvt<<<16448, 256, 0, stream>>>(KVacc, Ksum, KVt, KsumR);
    k_phiq_attn<<<dim3(16, 64), 512, 0, stream>>>(QK, wt, KVt, KsumR, attn);
    k_gemm_out<<<512, 512, 0, stream>>>(attn, Wof, bo, (float*)d_out);
}